// Round 6
// baseline (302.848 us; speedup 1.0000x reference)
//
#include <hip/hip_runtime.h>
#include <math.h>

#define NN 102400
#define NE 1638400
#define NG 2048
#define KTOP 30
#define NBUCK 400   // coarse buckets of 256 nodes (dst >> 8)
#define EPB 4096    // edges per pass-1 block
#define NB1 400     // NE / EPB

// ---------- fused front: coarse histogram + dense1 + starts + l1w transpose ----------
// blocks [0,400):      H1 — per-block coarse histogram of dst (LDS atomics only)
// blocks [400,1200):   dense x@W1 -> htmp
// blocks [1200,1600):  starts from sorted batch
// blocks [1600,1728):  l1w transpose -> l1wT[128][352]
__global__ __launch_bounds__(256) void fused_front_kernel(
    const int* __restrict__ dst, int* __restrict__ hist1,
    const float* __restrict__ x, const float* __restrict__ W1,
    float* __restrict__ htmp,
    const int* __restrict__ batch, int* __restrict__ starts,
    const float* __restrict__ l1w, float* __restrict__ l1wT) {
    __shared__ float Wsh[128 * 32];
    __shared__ int hsh[NBUCK];
    int bid = blockIdx.x;
    int tid = threadIdx.x;

    if (bid < NB1) {
        // ---- H1: coarse histogram (int4 edge reads) ----
        for (int q = tid; q < NBUCK; q += 256) hsh[q] = 0;
        __syncthreads();
        const int4* dp = (const int4*)(dst + bid * EPB);
        for (int i4 = tid; i4 < EPB / 4; i4 += 256) {
            int4 dd = dp[i4];
            atomicAdd(&hsh[dd.x >> 8], 1);
            atomicAdd(&hsh[dd.y >> 8], 1);
            atomicAdd(&hsh[dd.z >> 8], 1);
            atomicAdd(&hsh[dd.w >> 8], 1);
        }
        __syncthreads();
        for (int q = tid; q < NBUCK; q += 256) hist1[q * NB1 + bid] = hsh[q];
    } else if (bid < NB1 + 800) {
        // ---- dense1: 128 -> 32, 2 nodes x 8 outputs per thread ----
        int bidx = bid - NB1;
        for (int i = tid; i < 128 * 32; i += 256) Wsh[i] = W1[i];
        __syncthreads();
        int jb = (tid >> 6) << 3;
        int q = tid & 63;
        int n0 = bidx * 128 + q;
        int n1 = n0 + 64;
        const float* x0p = x + (size_t)n0 * 128;
        const float* x1p = x + (size_t)n1 * 128;
        float acc0[8], acc1[8];
#pragma unroll
        for (int j = 0; j < 8; ++j) { acc0[j] = 0.f; acc1[j] = 0.f; }
#pragma unroll 2
        for (int k = 0; k < 128; k += 4) {
            float4 xa = *(const float4*)(x0p + k);
            float4 xb = *(const float4*)(x1p + k);
            float xs0[4] = {xa.x, xa.y, xa.z, xa.w};
            float xs1[4] = {xb.x, xb.y, xb.z, xb.w};
#pragma unroll
            for (int kk = 0; kk < 4; ++kk) {
                float4 wlo = *(const float4*)&Wsh[(k + kk) * 32 + jb];
                float4 whi = *(const float4*)&Wsh[(k + kk) * 32 + jb + 4];
                float v0 = xs0[kk], v1 = xs1[kk];
                acc0[0] += v0 * wlo.x; acc0[1] += v0 * wlo.y;
                acc0[2] += v0 * wlo.z; acc0[3] += v0 * wlo.w;
                acc0[4] += v0 * whi.x; acc0[5] += v0 * whi.y;
                acc0[6] += v0 * whi.z; acc0[7] += v0 * whi.w;
                acc1[0] += v1 * wlo.x; acc1[1] += v1 * wlo.y;
                acc1[2] += v1 * wlo.z; acc1[3] += v1 * wlo.w;
                acc1[4] += v1 * whi.x; acc1[5] += v1 * whi.y;
                acc1[6] += v1 * whi.z; acc1[7] += v1 * whi.w;
            }
        }
        float4 o0 = {acc0[0], acc0[1], acc0[2], acc0[3]};
        float4 o1 = {acc0[4], acc0[5], acc0[6], acc0[7]};
        float4 o2 = {acc1[0], acc1[1], acc1[2], acc1[3]};
        float4 o3 = {acc1[4], acc1[5], acc1[6], acc1[7]};
        *(float4*)&htmp[(size_t)n0 * 32 + jb] = o0;
        *(float4*)&htmp[(size_t)n0 * 32 + jb + 4] = o1;
        *(float4*)&htmp[(size_t)n1 * 32 + jb] = o2;
        *(float4*)&htmp[(size_t)n1 * 32 + jb + 4] = o3;
    } else if (bid < NB1 + 800 + 400) {
        // ---- starts ----
        int i = (bid - NB1 - 800) * 256 + tid;
        if (i < NN) {
            int c = batch[i];
            int p = (i == 0) ? -1 : batch[i - 1];
            for (int g = p + 1; g <= c; ++g) starts[g] = i;
            if (i == NN - 1) {
                for (int g = c + 1; g <= NG; ++g) starts[g] = NN;
            }
        }
    } else {
        // ---- l1w transpose: l1wT[o][i] = l1w[i*128+o] ----
        int o = bid - (NB1 + 800 + 400);
        for (int i = tid; i < 352; i += 256) l1wT[o * 352 + i] = l1w[i * 128 + o];
    }
}

// ---------- S1a: per-bucket scan over blocks -> intra-bucket block offsets + totals ----------
__global__ __launch_bounds__(256) void s1a_kernel(const int* __restrict__ hist1,
                                                  int* __restrict__ offs,
                                                  int* __restrict__ totals) {
    __shared__ int A[512], B[512];
    int q = blockIdx.x, tid = threadIdx.x;
    int i0 = tid, i1 = tid + 256;
    int v0 = (i0 < NB1) ? hist1[q * NB1 + i0] : 0;
    int v1 = (i1 < NB1) ? hist1[q * NB1 + i1] : 0;
    A[i0] = v0; A[i1] = v1;
    __syncthreads();
    int* cur = A; int* nxt = B;
    for (int off = 1; off < 512; off <<= 1) {
        nxt[i0] = cur[i0] + ((i0 >= off) ? cur[i0 - off] : 0);
        nxt[i1] = cur[i1] + cur[i1 - off];
        __syncthreads();
        int* t = cur; cur = nxt; nxt = t;
    }
    if (i0 < NB1) offs[q * NB1 + i0] = cur[i0] - v0;
    if (i1 < NB1) offs[q * NB1 + i1] = cur[i1] - v1;
    if (tid == 0) totals[q] = cur[511];
}

// ---------- S1b: scan bucket totals -> bucketStart ----------
__global__ __launch_bounds__(256) void s1b_kernel(const int* __restrict__ totals,
                                                  int* __restrict__ bucketStart,
                                                  int* __restrict__ rowptr) {
    __shared__ int A[512], B[512];
    int tid = threadIdx.x;
    int i0 = tid, i1 = tid + 256;
    int v0 = (i0 < NBUCK) ? totals[i0] : 0;
    int v1 = (i1 < NBUCK) ? totals[i1] : 0;
    A[i0] = v0; A[i1] = v1;
    __syncthreads();
    int* cur = A; int* nxt = B;
    for (int off = 1; off < 512; off <<= 1) {
        nxt[i0] = cur[i0] + ((i0 >= off) ? cur[i0 - off] : 0);
        nxt[i1] = cur[i1] + cur[i1 - off];
        __syncthreads();
        int* t = cur; cur = nxt; nxt = t;
    }
    if (i0 < NBUCK) bucketStart[i0] = cur[i0] - v0;
    if (i1 < NBUCK) bucketStart[i1] = cur[i1] - v1;
    if (tid == 0) { bucketStart[NBUCK] = cur[511]; rowptr[NN] = cur[511]; }
}

// ---------- P1: scatter edges into coarse buckets (LDS-atomic slot assignment) ----------
// packed u32 = (dst & 255) << 24 | src   (src < 2^17)
__global__ __launch_bounds__(256) void p1_kernel(const int* __restrict__ src,
                                                 const int* __restrict__ dst,
                                                 const int* __restrict__ offs,
                                                 const int* __restrict__ bucketStart,
                                                 unsigned int* __restrict__ ebuf) {
    __shared__ int myoff[NBUCK];
    int b = blockIdx.x, tid = threadIdx.x;
    for (int q = tid; q < NBUCK; q += 256)
        myoff[q] = bucketStart[q] + offs[q * NB1 + b];
    __syncthreads();
    const int4* dp = (const int4*)(dst + b * EPB);
    const int4* sp = (const int4*)(src + b * EPB);
    for (int i4 = tid; i4 < EPB / 4; i4 += 256) {
        int4 dd = dp[i4];
        int4 ss = sp[i4];
        int p0 = atomicAdd(&myoff[dd.x >> 8], 1);
        int p1 = atomicAdd(&myoff[dd.y >> 8], 1);
        int p2 = atomicAdd(&myoff[dd.z >> 8], 1);
        int p3 = atomicAdd(&myoff[dd.w >> 8], 1);
        ebuf[p0] = ((unsigned int)(dd.x & 255) << 24) | (unsigned int)ss.x;
        ebuf[p1] = ((unsigned int)(dd.y & 255) << 24) | (unsigned int)ss.y;
        ebuf[p2] = ((unsigned int)(dd.z & 255) << 24) | (unsigned int)ss.z;
        ebuf[p3] = ((unsigned int)(dd.w & 255) << 24) | (unsigned int)ss.w;
    }
}

// ---------- P2: per-bucket fine counting sort -> csr_src + rowptr + dinv ----------
__global__ __launch_bounds__(256) void p2_kernel(const unsigned int* __restrict__ ebuf,
                                                 const int* __restrict__ bucketStart,
                                                 int* __restrict__ csr_src,
                                                 int* __restrict__ rowptr,
                                                 float* __restrict__ dinv) {
    __shared__ int fcnt[256];
    __shared__ int tmp[256];
    __shared__ int foff[256];
    int q = blockIdx.x, tid = threadIdx.x;
    int base = bucketStart[q];
    int ecnt = bucketStart[q + 1] - base;
    fcnt[tid] = 0;
    __syncthreads();
    for (int i = tid; i < ecnt; i += 256) {
        unsigned int e = ebuf[base + i];
        atomicAdd(&fcnt[e >> 24], 1);
    }
    __syncthreads();
    int c = fcnt[tid];
    int n = q * 256 + tid;
    dinv[n] = rsqrtf((float)c + 1.0f);
    tmp[tid] = c;
    __syncthreads();
    for (int off = 1; off < 256; off <<= 1) {
        int u = (tid >= off) ? tmp[tid - off] : 0;
        __syncthreads();
        tmp[tid] += u;
        __syncthreads();
    }
    int excl = base + tmp[tid] - c;
    rowptr[n] = excl;
    foff[tid] = excl;
    __syncthreads();
    for (int i = tid; i < ecnt; i += 256) {
        unsigned int e = ebuf[base + i];
        int pos = atomicAdd(&foff[e >> 24], 1);
        csr_src[pos] = (int)(e & 0xFFFFFF);
    }
}

// ---------- dense: tiled, 2 nodes x 8 outputs per thread (layers 2,3) ----------
template <int FIN>
__global__ __launch_bounds__(256) void dense_tile_kernel(const float* __restrict__ x,
                                                         const float* __restrict__ W,
                                                         float* __restrict__ out) {
    __shared__ float Wsh[FIN * 32];
    for (int i = threadIdx.x; i < FIN * 32; i += 256) Wsh[i] = W[i];
    __syncthreads();
    int jb = (threadIdx.x >> 6) << 3;
    int q = threadIdx.x & 63;
    int n0 = blockIdx.x * 128 + q;
    int n1 = n0 + 64;
    const float* x0p = x + (size_t)n0 * FIN;
    const float* x1p = x + (size_t)n1 * FIN;
    float acc0[8], acc1[8];
#pragma unroll
    for (int j = 0; j < 8; ++j) { acc0[j] = 0.f; acc1[j] = 0.f; }
#pragma unroll 2
    for (int k = 0; k < FIN; k += 4) {
        float4 xa = *(const float4*)(x0p + k);
        float4 xb = *(const float4*)(x1p + k);
        float xs0[4] = {xa.x, xa.y, xa.z, xa.w};
        float xs1[4] = {xb.x, xb.y, xb.z, xb.w};
#pragma unroll
        for (int kk = 0; kk < 4; ++kk) {
            float4 wlo = *(const float4*)&Wsh[(k + kk) * 32 + jb];
            float4 whi = *(const float4*)&Wsh[(k + kk) * 32 + jb + 4];
            float v0 = xs0[kk], v1 = xs1[kk];
            acc0[0] += v0 * wlo.x; acc0[1] += v0 * wlo.y;
            acc0[2] += v0 * wlo.z; acc0[3] += v0 * wlo.w;
            acc0[4] += v0 * whi.x; acc0[5] += v0 * whi.y;
            acc0[6] += v0 * whi.z; acc0[7] += v0 * whi.w;
            acc1[0] += v1 * wlo.x; acc1[1] += v1 * wlo.y;
            acc1[2] += v1 * wlo.z; acc1[3] += v1 * wlo.w;
            acc1[4] += v1 * whi.x; acc1[5] += v1 * whi.y;
            acc1[6] += v1 * whi.z; acc1[7] += v1 * whi.w;
        }
    }
    float4 o0 = {acc0[0], acc0[1], acc0[2], acc0[3]};
    float4 o1 = {acc0[4], acc0[5], acc0[6], acc0[7]};
    float4 o2 = {acc1[0], acc1[1], acc1[2], acc1[3]};
    float4 o3 = {acc1[4], acc1[5], acc1[6], acc1[7]};
    *(float4*)&out[(size_t)n0 * 32 + jb] = o0;
    *(float4*)&out[(size_t)n0 * 32 + jb + 4] = o1;
    *(float4*)&out[(size_t)n1 * 32 + jb] = o2;
    *(float4*)&out[(size_t)n1 * 32 + jb + 4] = o3;
}

// 32 -> 1 dense, float4 row loads
__global__ __launch_bounds__(256) void dense4_kernel(const float* __restrict__ x,
                                                     const float* __restrict__ W,
                                                     float* __restrict__ out) {
    __shared__ float Ws[32];
    if (threadIdx.x < 32) Ws[threadIdx.x] = W[threadIdx.x];
    __syncthreads();
    int n = blockIdx.x * 256 + threadIdx.x;
    if (n >= NN) return;
    const float4* xr = (const float4*)(x + (size_t)n * 32);
    float s = 0.f;
#pragma unroll
    for (int qq = 0; qq < 8; ++qq) {
        float4 v = xr[qq];
        float4 wv = *(const float4*)&Ws[qq * 4];
        s += v.x * wv.x; s += v.y * wv.y; s += v.z * wv.z; s += v.w * wv.w;
    }
    out[n] = s;
}

// ---------- fused gather-aggregate + self-term + bias + tanh ----------
// 8 lanes per node; idx/coef loaded once per lane and shfl-broadcast within
// the 8-lane group (same values, same ascending-i sum order -> bit-exact).

__global__ __launch_bounds__(256) void gcn_agg32v_kernel(
    const int* __restrict__ rowptr, const int* __restrict__ csr_src,
    const float* __restrict__ htmp, const float* __restrict__ dinv,
    const float* __restrict__ b, float* __restrict__ hout) {
    int idx = blockIdx.x * 256 + threadIdx.x;
    int n = idx >> 3, fg = (idx & 7) << 2;
    if (n >= NN) return;
    int lane7 = threadIdx.x & 7;
    int beg = rowptr[n], end = rowptr[n + 1];
    float di = dinv[n];
    float4 acc = {0.f, 0.f, 0.f, 0.f};
    int i = beg;
    for (; i + 7 < end; i += 8) {
        int smy = csr_src[i + lane7];
        float cmy = dinv[smy] * di;
        int s[8];
        float c[8];
#pragma unroll
        for (int k = 0; k < 8; ++k) {
            s[k] = __shfl(smy, k, 8);
            c[k] = __shfl(cmy, k, 8);
        }
        float4 v[8];
#pragma unroll
        for (int k = 0; k < 8; ++k) v[k] = *(const float4*)&htmp[(size_t)s[k] * 32 + fg];
#pragma unroll
        for (int k = 0; k < 8; ++k) {
            acc.x += v[k].x * c[k]; acc.y += v[k].y * c[k];
            acc.z += v[k].z * c[k]; acc.w += v[k].w * c[k];
        }
    }
    for (; i < end; ++i) {
        int s = csr_src[i];
        float c = dinv[s] * di;
        float4 v = *(const float4*)&htmp[(size_t)s * 32 + fg];
        acc.x += v.x * c; acc.y += v.y * c; acc.z += v.z * c; acc.w += v.w * c;
    }
    float dd = di * di;
    float4 hs = *(const float4*)&htmp[(size_t)n * 32 + fg];
    float4 bb = *(const float4*)&b[fg];
    float4 o;
    o.x = tanhf(acc.x + hs.x * dd + bb.x);
    o.y = tanhf(acc.y + hs.y * dd + bb.y);
    o.z = tanhf(acc.z + hs.z * dd + bb.z);
    o.w = tanhf(acc.w + hs.w * dd + bb.w);
    *(float4*)&hout[(size_t)n * 32 + fg] = o;
}

__global__ __launch_bounds__(256) void gcn_agg1_kernel(
    const int* __restrict__ rowptr, const int* __restrict__ csr_src,
    const float* __restrict__ htmp, const float* __restrict__ dinv,
    const float* __restrict__ b, float* __restrict__ hout) {
    int n = blockIdx.x * blockDim.x + threadIdx.x;
    if (n >= NN) return;
    int beg = rowptr[n], end = rowptr[n + 1];
    float di = dinv[n];
    float acc = 0.f;
    int i = beg;
    for (; i + 7 < end; i += 8) {
        int s[8];
#pragma unroll
        for (int k = 0; k < 8; ++k) s[k] = csr_src[i + k];
        float c[8], v[8];
#pragma unroll
        for (int k = 0; k < 8; ++k) c[k] = dinv[s[k]] * di;
#pragma unroll
        for (int k = 0; k < 8; ++k) v[k] = htmp[s[k]];
#pragma unroll
        for (int k = 0; k < 8; ++k) acc += v[k] * c[k];
    }
    for (; i < end; ++i) {
        int s = csr_src[i];
        acc += htmp[s] * (dinv[s] * di);
    }
    hout[n] = tanhf(acc + htmp[n] * di * di + b[0]);
}

// ---------- sort-pool + CNN head ----------

#define PSTR 100

__global__ __launch_bounds__(256) void pool_cnn_kernel(
    const float* __restrict__ h1, const float* __restrict__ h2,
    const float* __restrict__ h3, const float* __restrict__ h4,
    const int* __restrict__ starts,
    const float* __restrict__ c1w, const float* __restrict__ c1b,
    const float* __restrict__ c2w, const float* __restrict__ c2b,
    const float* __restrict__ l1wT, const float* __restrict__ l1b,
    const float* __restrict__ l2w, const float* __restrict__ l2b,
    float* __restrict__ out) {
    __shared__ float P[KTOP][PSTR];
    __shared__ float CW[16 * PSTR];
    __shared__ float KY[480];
    float* keys = KY;
    float* y2 = &P[0][0];
    float* y3 = &P[0][0] + 240;
    float* z  = &P[0][0] + 592;
    int g = blockIdx.x;
    int tid = threadIdx.x;

    int start = starts[g];
    int end = starts[g + 1];
    int cnt = end - start;

    for (int i = tid; i < KTOP * PSTR; i += 256) (&P[0][0])[i] = 0.f;
    for (int i = tid; i < 16 * 97; i += 256) {
        int c = i / 97, f = i % 97;
        CW[c * PSTR + f] = c1w[i];
    }
    bool fits = (cnt <= 256);
    if (fits) {
        for (int i = tid; i < cnt; i += 256) keys[i] = h4[start + i];
    }
    __syncthreads();

    for (int i = tid; i < cnt; i += 256) {
        float key = fits ? keys[i] : h4[start + i];
        int rank = 0;
        if (fits) {
            for (int j = 0; j < cnt; ++j) {
                float kj = keys[j];
                rank += (kj > key) || (kj == key && j < i);
            }
        } else {
            for (int j = 0; j < cnt; ++j) {
                float kj = h4[start + j];
                rank += (kj > key) || (kj == key && j < i);
            }
        }
        if (rank < KTOP) {
            int node = start + i;
            const float4* r1 = (const float4*)(h1 + (size_t)node * 32);
            const float4* r2 = (const float4*)(h2 + (size_t)node * 32);
            const float4* r3 = (const float4*)(h3 + (size_t)node * 32);
#pragma unroll
            for (int q = 0; q < 8; ++q) *(float4*)&P[rank][4 * q] = r1[q];
#pragma unroll
            for (int q = 0; q < 8; ++q) *(float4*)&P[rank][32 + 4 * q] = r2[q];
#pragma unroll
            for (int q = 0; q < 8; ++q) *(float4*)&P[rank][64 + 4 * q] = r3[q];
            P[rank][96] = key;
        }
    }
    __syncthreads();

    // conv1: o = t*16 + c mapping -> only 4 distinct P rows per wave (banks
    // 0/4/8/12, conflict-free) and 16 CW rows at 2-way (free). f ascending
    // accumulation -> bit-exact.
    for (int o = tid; o < 16 * KTOP; o += 256) {
        int t = o >> 4, c = o & 15;
        float s = c1b[c];
        const float* Pr = &P[t][0];
        const float* Wr = &CW[c * PSTR];
#pragma unroll
        for (int f4 = 0; f4 < 24; ++f4) {
            float4 pv = *(const float4*)(Pr + 4 * f4);
            float4 wv = *(const float4*)(Wr + 4 * f4);
            s += wv.x * pv.x; s += wv.y * pv.y; s += wv.z * pv.z; s += wv.w * pv.w;
        }
        s += Wr[96] * Pr[96];
        KY[c * KTOP + t] = fmaxf(s, 0.f);
    }
    __syncthreads();

    for (int o = tid; o < 16 * 15; o += 256) {
        int c = o / 15, t = o % 15;
        y2[o] = fmaxf(KY[c * KTOP + 2 * t], KY[c * KTOP + 2 * t + 1]);
    }
    __syncthreads();

    for (int o = tid; o < 32 * 11; o += 256) {
        int c = o / 11, t = o % 11;
        float s = c2b[c];
#pragma unroll
        for (int i = 0; i < 16; ++i)
#pragma unroll
            for (int j = 0; j < 5; ++j)
                s += c2w[(c * 16 + i) * 5 + j] * y2[i * 15 + t + j];
        y3[o] = fmaxf(s, 0.f);
    }
    __syncthreads();

    // l1: transposed weights, float4 streaming (4x fewer load issues),
    // i ascending scalar accumulation -> bit-exact.
    for (int o = tid; o < 128; o += 256) {
        float s = l1b[o];
        const float4* wr = (const float4*)(l1wT + (size_t)o * 352);
#pragma unroll 8
        for (int i4 = 0; i4 < 88; ++i4) {
            float4 wv = wr[i4];
            float4 yv = *(const float4*)&y3[4 * i4];
            s += yv.x * wv.x; s += yv.y * wv.y; s += yv.z * wv.z; s += yv.w * wv.w;
        }
        z[o] = fmaxf(s, 0.f);
    }
    __syncthreads();

    if (tid == 0) {
        float s = l2b[0];
#pragma unroll 4
        for (int i = 0; i < 128; ++i) s += z[i] * l2w[i];
        out[g] = 1.f / (1.f + expf(-s));
    }
}

extern "C" void kernel_launch(void* const* d_in, const int* in_sizes, int n_in,
                              void* d_out, int out_size, void* d_ws, size_t ws_size,
                              hipStream_t stream) {
    const float* x   = (const float*)d_in[0];
    const int* ei    = (const int*)d_in[1];
    const int* batch = (const int*)d_in[2];
    const float* W1  = (const float*)d_in[3];
    const float* b1  = (const float*)d_in[4];
    const float* W2  = (const float*)d_in[5];
    const float* b2  = (const float*)d_in[6];
    const float* W3  = (const float*)d_in[7];
    const float* b3  = (const float*)d_in[8];
    const float* W4  = (const float*)d_in[9];
    const float* b4  = (const float*)d_in[10];
    const float* c1w = (const float*)d_in[11];
    const float* c1b = (const float*)d_in[12];
    const float* c2w = (const float*)d_in[13];
    const float* c2b = (const float*)d_in[14];
    const float* l1w = (const float*)d_in[15];
    const float* l1b = (const float*)d_in[16];
    const float* l2w = (const float*)d_in[17];
    const float* l2b = (const float*)d_in[18];
    float* out = (float*)d_out;

    const int* srcp = ei;
    const int* dstp = ei + NE;

    // workspace layout
    char* w = (char*)d_ws;
    float* dinv      = (float*)w;               w += sizeof(float) * NN;
    float* htmp      = (float*)w;               w += sizeof(float) * NN * 32;
    float* h1        = (float*)w;               w += sizeof(float) * NN * 32;
    float* h2        = (float*)w;               w += sizeof(float) * NN * 32;  // ebuf aliases here
    float* h3        = (float*)w;               w += sizeof(float) * NN * 32;
    float* h4        = (float*)w;               w += sizeof(float) * NN;
    int*   rowptr    = (int*)w;                 w += sizeof(int) * (NN + 1);
    int*   hist1     = (int*)w;                 w += sizeof(int) * NBUCK * NB1;
    int*   offs      = (int*)w;                 w += sizeof(int) * NBUCK * NB1;
    int*   totals    = (int*)w;                 w += sizeof(int) * NBUCK;
    int*   bucketStart = (int*)w;               w += sizeof(int) * (NBUCK + 1);
    int*   csr_src   = (int*)w;                 w += sizeof(int) * NE;
    float* l1wT      = (float*)w;               w += sizeof(float) * 128 * 352;
    int*   starts    = (int*)w;                 w += sizeof(int) * (NG + 1);

    // ebuf (NE u32 = 6.55 MB) aliases h2 (13.1 MB) — h2 is written only at layer-2,
    // long after P2 has consumed ebuf.
    unsigned int* ebuf = (unsigned int*)h2;

    // fused front: coarse histogram + dense1 + starts + l1w transpose
    fused_front_kernel<<<NB1 + 800 + 400 + 128, 256, 0, stream>>>(
        dstp, hist1, x, W1, htmp, batch, starts, l1w, l1wT);
    s1a_kernel<<<NBUCK, 256, 0, stream>>>(hist1, offs, totals);
    s1b_kernel<<<1, 256, 0, stream>>>(totals, bucketStart, rowptr);
    p1_kernel<<<NB1, 256, 0, stream>>>(srcp, dstp, offs, bucketStart, ebuf);
    p2_kernel<<<NBUCK, 256, 0, stream>>>(ebuf, bucketStart, csr_src, rowptr, dinv);

    // layer 1 aggregate (dense1 already done in fused front)
    gcn_agg32v_kernel<<<NN * 8 / 256, 256, 0, stream>>>(rowptr, csr_src, htmp, dinv, b1, h1);

    // layer 2: 32 -> 32
    dense_tile_kernel<32><<<NN / 128, 256, 0, stream>>>(h1, W2, htmp);
    gcn_agg32v_kernel<<<NN * 8 / 256, 256, 0, stream>>>(rowptr, csr_src, htmp, dinv, b2, h2);

    // layer 3: 32 -> 32
    dense_tile_kernel<32><<<NN / 128, 256, 0, stream>>>(h2, W3, htmp);
    gcn_agg32v_kernel<<<NN * 8 / 256, 256, 0, stream>>>(rowptr, csr_src, htmp, dinv, b3, h3);

    // layer 4: 32 -> 1
    dense4_kernel<<<NN / 256, 256, 0, stream>>>(h3, W4, htmp);
    gcn_agg1_kernel<<<NN / 256, 256, 0, stream>>>(rowptr, csr_src, htmp, dinv, b4, h4);

    // fused sort-pool + CNN head
    pool_cnn_kernel<<<NG, 256, 0, stream>>>(h1, h2, h3, h4, starts,
                                            c1w, c1b, c2w, c2b,
                                            l1wT, l1b, l2w, l2b, out);
}

// Round 7
// 274.085 us; speedup vs baseline: 1.1049x; 1.1049x over previous
//
#include <hip/hip_runtime.h>
#include <math.h>

#define NN 102400
#define NE 1638400
#define NG 2048
#define KTOP 30
#define NBUCK 400   // coarse buckets of 256 nodes (dst >> 8)
#define EPB 4096    // edges per pass-1 block
#define NB1 400     // NE / EPB

// ---------- fused front: coarse histogram + dense1 + starts ----------
// blocks [0,400):      H1 — per-block coarse histogram of dst (LDS atomics only)
// blocks [400,1200):   dense x@W1 -> htmp
// blocks [1200,1600):  starts from sorted batch
__global__ __launch_bounds__(256) void fused_front_kernel(
    const int* __restrict__ dst, int* __restrict__ hist1,
    const float* __restrict__ x, const float* __restrict__ W1,
    float* __restrict__ htmp,
    const int* __restrict__ batch, int* __restrict__ starts) {
    __shared__ float Wsh[128 * 32];
    __shared__ int hsh[NBUCK];
    int bid = blockIdx.x;
    int tid = threadIdx.x;

    if (bid < NB1) {
        // ---- H1: coarse histogram (int4 edge reads) ----
        for (int q = tid; q < NBUCK; q += 256) hsh[q] = 0;
        __syncthreads();
        const int4* dp = (const int4*)(dst + bid * EPB);
        for (int i4 = tid; i4 < EPB / 4; i4 += 256) {
            int4 dd = dp[i4];
            atomicAdd(&hsh[dd.x >> 8], 1);
            atomicAdd(&hsh[dd.y >> 8], 1);
            atomicAdd(&hsh[dd.z >> 8], 1);
            atomicAdd(&hsh[dd.w >> 8], 1);
        }
        __syncthreads();
        for (int q = tid; q < NBUCK; q += 256) hist1[q * NB1 + bid] = hsh[q];
    } else if (bid < NB1 + 800) {
        // ---- dense1: 128 -> 32, 2 nodes x 8 outputs per thread ----
        int bidx = bid - NB1;
        for (int i = tid; i < 128 * 32; i += 256) Wsh[i] = W1[i];
        __syncthreads();
        int jb = (tid >> 6) << 3;
        int q = tid & 63;
        int n0 = bidx * 128 + q;
        int n1 = n0 + 64;
        const float* x0p = x + (size_t)n0 * 128;
        const float* x1p = x + (size_t)n1 * 128;
        float acc0[8], acc1[8];
#pragma unroll
        for (int j = 0; j < 8; ++j) { acc0[j] = 0.f; acc1[j] = 0.f; }
#pragma unroll 2
        for (int k = 0; k < 128; k += 4) {
            float4 xa = *(const float4*)(x0p + k);
            float4 xb = *(const float4*)(x1p + k);
            float xs0[4] = {xa.x, xa.y, xa.z, xa.w};
            float xs1[4] = {xb.x, xb.y, xb.z, xb.w};
#pragma unroll
            for (int kk = 0; kk < 4; ++kk) {
                float4 wlo = *(const float4*)&Wsh[(k + kk) * 32 + jb];
                float4 whi = *(const float4*)&Wsh[(k + kk) * 32 + jb + 4];
                float v0 = xs0[kk], v1 = xs1[kk];
                acc0[0] += v0 * wlo.x; acc0[1] += v0 * wlo.y;
                acc0[2] += v0 * wlo.z; acc0[3] += v0 * wlo.w;
                acc0[4] += v0 * whi.x; acc0[5] += v0 * whi.y;
                acc0[6] += v0 * whi.z; acc0[7] += v0 * whi.w;
                acc1[0] += v1 * wlo.x; acc1[1] += v1 * wlo.y;
                acc1[2] += v1 * wlo.z; acc1[3] += v1 * wlo.w;
                acc1[4] += v1 * whi.x; acc1[5] += v1 * whi.y;
                acc1[6] += v1 * whi.z; acc1[7] += v1 * whi.w;
            }
        }
        float4 o0 = {acc0[0], acc0[1], acc0[2], acc0[3]};
        float4 o1 = {acc0[4], acc0[5], acc0[6], acc0[7]};
        float4 o2 = {acc1[0], acc1[1], acc1[2], acc1[3]};
        float4 o3 = {acc1[4], acc1[5], acc1[6], acc1[7]};
        *(float4*)&htmp[(size_t)n0 * 32 + jb] = o0;
        *(float4*)&htmp[(size_t)n0 * 32 + jb + 4] = o1;
        *(float4*)&htmp[(size_t)n1 * 32 + jb] = o2;
        *(float4*)&htmp[(size_t)n1 * 32 + jb + 4] = o3;
    } else {
        // ---- starts ----
        int i = (bid - NB1 - 800) * 256 + tid;
        if (i < NN) {
            int c = batch[i];
            int p = (i == 0) ? -1 : batch[i - 1];
            for (int g = p + 1; g <= c; ++g) starts[g] = i;
            if (i == NN - 1) {
                for (int g = c + 1; g <= NG; ++g) starts[g] = NN;
            }
        }
    }
}

// ---------- S1a: per-bucket scan over blocks -> intra-bucket block offsets + totals ----------
__global__ __launch_bounds__(256) void s1a_kernel(const int* __restrict__ hist1,
                                                  int* __restrict__ offs,
                                                  int* __restrict__ totals) {
    __shared__ int A[512], B[512];
    int q = blockIdx.x, tid = threadIdx.x;
    int i0 = tid, i1 = tid + 256;
    int v0 = (i0 < NB1) ? hist1[q * NB1 + i0] : 0;
    int v1 = (i1 < NB1) ? hist1[q * NB1 + i1] : 0;
    A[i0] = v0; A[i1] = v1;
    __syncthreads();
    int* cur = A; int* nxt = B;
    for (int off = 1; off < 512; off <<= 1) {
        nxt[i0] = cur[i0] + ((i0 >= off) ? cur[i0 - off] : 0);
        nxt[i1] = cur[i1] + cur[i1 - off];
        __syncthreads();
        int* t = cur; cur = nxt; nxt = t;
    }
    if (i0 < NB1) offs[q * NB1 + i0] = cur[i0] - v0;
    if (i1 < NB1) offs[q * NB1 + i1] = cur[i1] - v1;
    if (tid == 0) totals[q] = cur[511];
}

// ---------- S1b: scan bucket totals -> bucketStart ----------
__global__ __launch_bounds__(256) void s1b_kernel(const int* __restrict__ totals,
                                                  int* __restrict__ bucketStart,
                                                  int* __restrict__ rowptr) {
    __shared__ int A[512], B[512];
    int tid = threadIdx.x;
    int i0 = tid, i1 = tid + 256;
    int v0 = (i0 < NBUCK) ? totals[i0] : 0;
    int v1 = (i1 < NBUCK) ? totals[i1] : 0;
    A[i0] = v0; A[i1] = v1;
    __syncthreads();
    int* cur = A; int* nxt = B;
    for (int off = 1; off < 512; off <<= 1) {
        nxt[i0] = cur[i0] + ((i0 >= off) ? cur[i0 - off] : 0);
        nxt[i1] = cur[i1] + cur[i1 - off];
        __syncthreads();
        int* t = cur; cur = nxt; nxt = t;
    }
    if (i0 < NBUCK) bucketStart[i0] = cur[i0] - v0;
    if (i1 < NBUCK) bucketStart[i1] = cur[i1] - v1;
    if (tid == 0) { bucketStart[NBUCK] = cur[511]; rowptr[NN] = cur[511]; }
}

// ---------- P1: scatter edges into coarse buckets (LDS-atomic slot assignment) ----------
// packed u32 = (dst & 255) << 24 | src   (src < 2^17)
__global__ __launch_bounds__(256) void p1_kernel(const int* __restrict__ src,
                                                 const int* __restrict__ dst,
                                                 const int* __restrict__ offs,
                                                 const int* __restrict__ bucketStart,
                                                 unsigned int* __restrict__ ebuf) {
    __shared__ int myoff[NBUCK];
    int b = blockIdx.x, tid = threadIdx.x;
    for (int q = tid; q < NBUCK; q += 256)
        myoff[q] = bucketStart[q] + offs[q * NB1 + b];
    __syncthreads();
    const int4* dp = (const int4*)(dst + b * EPB);
    const int4* sp = (const int4*)(src + b * EPB);
    for (int i4 = tid; i4 < EPB / 4; i4 += 256) {
        int4 dd = dp[i4];
        int4 ss = sp[i4];
        int p0 = atomicAdd(&myoff[dd.x >> 8], 1);
        int p1 = atomicAdd(&myoff[dd.y >> 8], 1);
        int p2 = atomicAdd(&myoff[dd.z >> 8], 1);
        int p3 = atomicAdd(&myoff[dd.w >> 8], 1);
        ebuf[p0] = ((unsigned int)(dd.x & 255) << 24) | (unsigned int)ss.x;
        ebuf[p1] = ((unsigned int)(dd.y & 255) << 24) | (unsigned int)ss.y;
        ebuf[p2] = ((unsigned int)(dd.z & 255) << 24) | (unsigned int)ss.z;
        ebuf[p3] = ((unsigned int)(dd.w & 255) << 24) | (unsigned int)ss.w;
    }
}

// ---------- P2: per-bucket fine counting sort -> csr_src + rowptr + dinv ----------
__global__ __launch_bounds__(256) void p2_kernel(const unsigned int* __restrict__ ebuf,
                                                 const int* __restrict__ bucketStart,
                                                 int* __restrict__ csr_src,
                                                 int* __restrict__ rowptr,
                                                 float* __restrict__ dinv) {
    __shared__ int fcnt[256];
    __shared__ int tmp[256];
    __shared__ int foff[256];
    int q = blockIdx.x, tid = threadIdx.x;
    int base = bucketStart[q];
    int ecnt = bucketStart[q + 1] - base;
    fcnt[tid] = 0;
    __syncthreads();
    for (int i = tid; i < ecnt; i += 256) {
        unsigned int e = ebuf[base + i];
        atomicAdd(&fcnt[e >> 24], 1);
    }
    __syncthreads();
    int c = fcnt[tid];
    int n = q * 256 + tid;
    dinv[n] = rsqrtf((float)c + 1.0f);
    tmp[tid] = c;
    __syncthreads();
    for (int off = 1; off < 256; off <<= 1) {
        int u = (tid >= off) ? tmp[tid - off] : 0;
        __syncthreads();
        tmp[tid] += u;
        __syncthreads();
    }
    int excl = base + tmp[tid] - c;
    rowptr[n] = excl;
    foff[tid] = excl;
    __syncthreads();
    for (int i = tid; i < ecnt; i += 256) {
        unsigned int e = ebuf[base + i];
        int pos = atomicAdd(&foff[e >> 24], 1);
        csr_src[pos] = (int)(e & 0xFFFFFF);
    }
}

// ---------- dense: tiled, 2 nodes x 8 outputs per thread (layers 2,3) ----------
template <int FIN>
__global__ __launch_bounds__(256) void dense_tile_kernel(const float* __restrict__ x,
                                                         const float* __restrict__ W,
                                                         float* __restrict__ out) {
    __shared__ float Wsh[FIN * 32];
    for (int i = threadIdx.x; i < FIN * 32; i += 256) Wsh[i] = W[i];
    __syncthreads();
    int jb = (threadIdx.x >> 6) << 3;
    int q = threadIdx.x & 63;
    int n0 = blockIdx.x * 128 + q;
    int n1 = n0 + 64;
    const float* x0p = x + (size_t)n0 * FIN;
    const float* x1p = x + (size_t)n1 * FIN;
    float acc0[8], acc1[8];
#pragma unroll
    for (int j = 0; j < 8; ++j) { acc0[j] = 0.f; acc1[j] = 0.f; }
#pragma unroll 2
    for (int k = 0; k < FIN; k += 4) {
        float4 xa = *(const float4*)(x0p + k);
        float4 xb = *(const float4*)(x1p + k);
        float xs0[4] = {xa.x, xa.y, xa.z, xa.w};
        float xs1[4] = {xb.x, xb.y, xb.z, xb.w};
#pragma unroll
        for (int kk = 0; kk < 4; ++kk) {
            float4 wlo = *(const float4*)&Wsh[(k + kk) * 32 + jb];
            float4 whi = *(const float4*)&Wsh[(k + kk) * 32 + jb + 4];
            float v0 = xs0[kk], v1 = xs1[kk];
            acc0[0] += v0 * wlo.x; acc0[1] += v0 * wlo.y;
            acc0[2] += v0 * wlo.z; acc0[3] += v0 * wlo.w;
            acc0[4] += v0 * whi.x; acc0[5] += v0 * whi.y;
            acc0[6] += v0 * whi.z; acc0[7] += v0 * whi.w;
            acc1[0] += v1 * wlo.x; acc1[1] += v1 * wlo.y;
            acc1[2] += v1 * wlo.z; acc1[3] += v1 * wlo.w;
            acc1[4] += v1 * whi.x; acc1[5] += v1 * whi.y;
            acc1[6] += v1 * whi.z; acc1[7] += v1 * whi.w;
        }
    }
    float4 o0 = {acc0[0], acc0[1], acc0[2], acc0[3]};
    float4 o1 = {acc0[4], acc0[5], acc0[6], acc0[7]};
    float4 o2 = {acc1[0], acc1[1], acc1[2], acc1[3]};
    float4 o3 = {acc1[4], acc1[5], acc1[6], acc1[7]};
    *(float4*)&out[(size_t)n0 * 32 + jb] = o0;
    *(float4*)&out[(size_t)n0 * 32 + jb + 4] = o1;
    *(float4*)&out[(size_t)n1 * 32 + jb] = o2;
    *(float4*)&out[(size_t)n1 * 32 + jb + 4] = o3;
}

// 32 -> 1 dense, float4 row loads
__global__ __launch_bounds__(256) void dense4_kernel(const float* __restrict__ x,
                                                     const float* __restrict__ W,
                                                     float* __restrict__ out) {
    __shared__ float Ws[32];
    if (threadIdx.x < 32) Ws[threadIdx.x] = W[threadIdx.x];
    __syncthreads();
    int n = blockIdx.x * 256 + threadIdx.x;
    if (n >= NN) return;
    const float4* xr = (const float4*)(x + (size_t)n * 32);
    float s = 0.f;
#pragma unroll
    for (int qq = 0; qq < 8; ++qq) {
        float4 v = xr[qq];
        float4 wv = *(const float4*)&Ws[qq * 4];
        s += v.x * wv.x; s += v.y * wv.y; s += v.z * wv.z; s += v.w * wv.w;
    }
    out[n] = s;
}

// ---------- fused gather-aggregate + self-term + bias + tanh ----------
// 8 lanes per node, float4 per lane; 8-deep independent gather chains.
// Accumulation strictly ascends i into one accumulator -> bit-identical order.

__global__ __launch_bounds__(256) void gcn_agg32v_kernel(
    const int* __restrict__ rowptr, const int* __restrict__ csr_src,
    const float* __restrict__ htmp, const float* __restrict__ dinv,
    const float* __restrict__ b, float* __restrict__ hout) {
    int idx = blockIdx.x * 256 + threadIdx.x;
    int n = idx >> 3, fg = (idx & 7) << 2;
    if (n >= NN) return;
    int beg = rowptr[n], end = rowptr[n + 1];
    float di = dinv[n];
    float4 acc = {0.f, 0.f, 0.f, 0.f};
    int i = beg;
    for (; i + 7 < end; i += 8) {
        int s[8];
#pragma unroll
        for (int k = 0; k < 8; ++k) s[k] = csr_src[i + k];
        float c[8];
#pragma unroll
        for (int k = 0; k < 8; ++k) c[k] = dinv[s[k]] * di;
        float4 v[8];
#pragma unroll
        for (int k = 0; k < 8; ++k) v[k] = *(const float4*)&htmp[(size_t)s[k] * 32 + fg];
#pragma unroll
        for (int k = 0; k < 8; ++k) {
            acc.x += v[k].x * c[k]; acc.y += v[k].y * c[k];
            acc.z += v[k].z * c[k]; acc.w += v[k].w * c[k];
        }
    }
    for (; i + 3 < end; i += 4) {
        int s0 = csr_src[i], s1 = csr_src[i + 1];
        int s2 = csr_src[i + 2], s3 = csr_src[i + 3];
        float c0 = dinv[s0] * di, c1 = dinv[s1] * di;
        float c2 = dinv[s2] * di, c3 = dinv[s3] * di;
        float4 v0 = *(const float4*)&htmp[(size_t)s0 * 32 + fg];
        float4 v1 = *(const float4*)&htmp[(size_t)s1 * 32 + fg];
        float4 v2 = *(const float4*)&htmp[(size_t)s2 * 32 + fg];
        float4 v3 = *(const float4*)&htmp[(size_t)s3 * 32 + fg];
        acc.x += v0.x * c0; acc.y += v0.y * c0; acc.z += v0.z * c0; acc.w += v0.w * c0;
        acc.x += v1.x * c1; acc.y += v1.y * c1; acc.z += v1.z * c1; acc.w += v1.w * c1;
        acc.x += v2.x * c2; acc.y += v2.y * c2; acc.z += v2.z * c2; acc.w += v2.w * c2;
        acc.x += v3.x * c3; acc.y += v3.y * c3; acc.z += v3.z * c3; acc.w += v3.w * c3;
    }
    for (; i < end; ++i) {
        int s = csr_src[i];
        float c = dinv[s] * di;
        float4 v = *(const float4*)&htmp[(size_t)s * 32 + fg];
        acc.x += v.x * c; acc.y += v.y * c; acc.z += v.z * c; acc.w += v.w * c;
    }
    float dd = di * di;
    float4 hs = *(const float4*)&htmp[(size_t)n * 32 + fg];
    float4 bb = *(const float4*)&b[fg];
    float4 o;
    o.x = tanhf(acc.x + hs.x * dd + bb.x);
    o.y = tanhf(acc.y + hs.y * dd + bb.y);
    o.z = tanhf(acc.z + hs.z * dd + bb.z);
    o.w = tanhf(acc.w + hs.w * dd + bb.w);
    *(float4*)&hout[(size_t)n * 32 + fg] = o;
}

__global__ __launch_bounds__(256) void gcn_agg1_kernel(
    const int* __restrict__ rowptr, const int* __restrict__ csr_src,
    const float* __restrict__ htmp, const float* __restrict__ dinv,
    const float* __restrict__ b, float* __restrict__ hout) {
    int n = blockIdx.x * blockDim.x + threadIdx.x;
    if (n >= NN) return;
    int beg = rowptr[n], end = rowptr[n + 1];
    float di = dinv[n];
    float acc = 0.f;
    int i = beg;
    for (; i + 7 < end; i += 8) {
        int s[8];
#pragma unroll
        for (int k = 0; k < 8; ++k) s[k] = csr_src[i + k];
        float c[8], v[8];
#pragma unroll
        for (int k = 0; k < 8; ++k) c[k] = dinv[s[k]] * di;
#pragma unroll
        for (int k = 0; k < 8; ++k) v[k] = htmp[s[k]];
#pragma unroll
        for (int k = 0; k < 8; ++k) acc += v[k] * c[k];
    }
    for (; i < end; ++i) {
        int s = csr_src[i];
        acc += htmp[s] * (dinv[s] * di);
    }
    hout[n] = tanhf(acc + htmp[n] * di * di + b[0]);
}

// ---------- sort-pool + CNN head ----------

#define PSTR 100

__global__ __launch_bounds__(256) void pool_cnn_kernel(
    const float* __restrict__ h1, const float* __restrict__ h2,
    const float* __restrict__ h3, const float* __restrict__ h4,
    const int* __restrict__ starts,
    const float* __restrict__ c1w, const float* __restrict__ c1b,
    const float* __restrict__ c2w, const float* __restrict__ c2b,
    const float* __restrict__ l1w, const float* __restrict__ l1b,
    const float* __restrict__ l2w, const float* __restrict__ l2b,
    float* __restrict__ out) {
    __shared__ float P[KTOP][PSTR];
    __shared__ float CW[16 * PSTR];
    __shared__ float KY[480];
    float* keys = KY;
    float* y2 = &P[0][0];
    float* y3 = &P[0][0] + 240;
    float* z  = &P[0][0] + 592;
    int g = blockIdx.x;
    int tid = threadIdx.x;

    int start = starts[g];
    int end = starts[g + 1];
    int cnt = end - start;

    for (int i = tid; i < KTOP * PSTR; i += 256) (&P[0][0])[i] = 0.f;
    for (int i = tid; i < 16 * 97; i += 256) {
        int c = i / 97, f = i % 97;
        CW[c * PSTR + f] = c1w[i];
    }
    bool fits = (cnt <= 256);
    if (fits) {
        for (int i = tid; i < cnt; i += 256) keys[i] = h4[start + i];
    }
    __syncthreads();

    for (int i = tid; i < cnt; i += 256) {
        float key = fits ? keys[i] : h4[start + i];
        int rank = 0;
        if (fits) {
            for (int j = 0; j < cnt; ++j) {
                float kj = keys[j];
                rank += (kj > key) || (kj == key && j < i);
            }
        } else {
            for (int j = 0; j < cnt; ++j) {
                float kj = h4[start + j];
                rank += (kj > key) || (kj == key && j < i);
            }
        }
        if (rank < KTOP) {
            int node = start + i;
            const float4* r1 = (const float4*)(h1 + (size_t)node * 32);
            const float4* r2 = (const float4*)(h2 + (size_t)node * 32);
            const float4* r3 = (const float4*)(h3 + (size_t)node * 32);
#pragma unroll
            for (int q = 0; q < 8; ++q) *(float4*)&P[rank][4 * q] = r1[q];
#pragma unroll
            for (int q = 0; q < 8; ++q) *(float4*)&P[rank][32 + 4 * q] = r2[q];
#pragma unroll
            for (int q = 0; q < 8; ++q) *(float4*)&P[rank][64 + 4 * q] = r3[q];
            P[rank][96] = key;
        }
    }
    __syncthreads();

    // conv1: o = t*16 + c mapping -> only 4 distinct P rows per wave (banks
    // 0/4/8/12, conflict-free broadcast) and 16 CW rows at 2-way (free).
    // f ascending accumulation -> bit-exact.
    for (int o = tid; o < 16 * KTOP; o += 256) {
        int t = o >> 4, c = o & 15;
        float s = c1b[c];
        const float* Pr = &P[t][0];
        const float* Wr = &CW[c * PSTR];
#pragma unroll
        for (int f4 = 0; f4 < 24; ++f4) {
            float4 pv = *(const float4*)(Pr + 4 * f4);
            float4 wv = *(const float4*)(Wr + 4 * f4);
            s += wv.x * pv.x; s += wv.y * pv.y; s += wv.z * pv.z; s += wv.w * pv.w;
        }
        s += Wr[96] * Pr[96];
        KY[c * KTOP + t] = fmaxf(s, 0.f);
    }
    __syncthreads();

    for (int o = tid; o < 16 * 15; o += 256) {
        int c = o / 15, t = o % 15;
        y2[o] = fmaxf(KY[c * KTOP + 2 * t], KY[c * KTOP + 2 * t + 1]);
    }
    __syncthreads();

    for (int o = tid; o < 32 * 11; o += 256) {
        int c = o / 11, t = o % 11;
        float s = c2b[c];
#pragma unroll
        for (int i = 0; i < 16; ++i)
#pragma unroll
            for (int j = 0; j < 5; ++j)
                s += c2w[(c * 16 + i) * 5 + j] * y2[i * 15 + t + j];
        y3[o] = fmaxf(s, 0.f);
    }
    __syncthreads();

    // l1: coalesced stride-128 weight loads (lane o -> l1w[i*128+o]),
    // deep unroll for load pipelining; i ascending -> bit-exact.
    for (int o = tid; o < 128; o += 256) {
        float s = l1b[o];
#pragma unroll 16
        for (int i = 0; i < 352; ++i) s += y3[i] * l1w[i * 128 + o];
        z[o] = fmaxf(s, 0.f);
    }
    __syncthreads();

    if (tid == 0) {
        float s = l2b[0];
#pragma unroll 4
        for (int i = 0; i < 128; ++i) s += z[i] * l2w[i];
        out[g] = 1.f / (1.f + expf(-s));
    }
}

extern "C" void kernel_launch(void* const* d_in, const int* in_sizes, int n_in,
                              void* d_out, int out_size, void* d_ws, size_t ws_size,
                              hipStream_t stream) {
    const float* x   = (const float*)d_in[0];
    const int* ei    = (const int*)d_in[1];
    const int* batch = (const int*)d_in[2];
    const float* W1  = (const float*)d_in[3];
    const float* b1  = (const float*)d_in[4];
    const float* W2  = (const float*)d_in[5];
    const float* b2  = (const float*)d_in[6];
    const float* W3  = (const float*)d_in[7];
    const float* b3  = (const float*)d_in[8];
    const float* W4  = (const float*)d_in[9];
    const float* b4  = (const float*)d_in[10];
    const float* c1w = (const float*)d_in[11];
    const float* c1b = (const float*)d_in[12];
    const float* c2w = (const float*)d_in[13];
    const float* c2b = (const float*)d_in[14];
    const float* l1w = (const float*)d_in[15];
    const float* l1b = (const float*)d_in[16];
    const float* l2w = (const float*)d_in[17];
    const float* l2b = (const float*)d_in[18];
    float* out = (float*)d_out;

    const int* srcp = ei;
    const int* dstp = ei + NE;

    // workspace layout
    char* w = (char*)d_ws;
    float* dinv      = (float*)w;               w += sizeof(float) * NN;
    float* htmp      = (float*)w;               w += sizeof(float) * NN * 32;
    float* h1        = (float*)w;               w += sizeof(float) * NN * 32;
    float* h2        = (float*)w;               w += sizeof(float) * NN * 32;  // ebuf aliases here
    float* h3        = (float*)w;               w += sizeof(float) * NN * 32;
    float* h4        = (float*)w;               w += sizeof(float) * NN;
    int*   rowptr    = (int*)w;                 w += sizeof(int) * (NN + 1);
    int*   hist1     = (int*)w;                 w += sizeof(int) * NBUCK * NB1;
    int*   offs      = (int*)w;                 w += sizeof(int) * NBUCK * NB1;
    int*   totals    = (int*)w;                 w += sizeof(int) * NBUCK;
    int*   bucketStart = (int*)w;               w += sizeof(int) * (NBUCK + 1);
    int*   csr_src   = (int*)w;                 w += sizeof(int) * NE;
    int*   starts    = (int*)w;                 w += sizeof(int) * (NG + 1);

    // ebuf (NE u32 = 6.55 MB) aliases h2 (13.1 MB) — h2 is written only at layer-2,
    // long after P2 has consumed ebuf.
    unsigned int* ebuf = (unsigned int*)h2;

    // fused front: coarse histogram + dense1 + starts (no global atomics anywhere)
    fused_front_kernel<<<NB1 + 800 + 400, 256, 0, stream>>>(dstp, hist1, x, W1, htmp,
                                                            batch, starts);
    s1a_kernel<<<NBUCK, 256, 0, stream>>>(hist1, offs, totals);
    s1b_kernel<<<1, 256, 0, stream>>>(totals, bucketStart, rowptr);
    p1_kernel<<<NB1, 256, 0, stream>>>(srcp, dstp, offs, bucketStart, ebuf);
    p2_kernel<<<NBUCK, 256, 0, stream>>>(ebuf, bucketStart, csr_src, rowptr, dinv);

    // layer 1 aggregate (dense1 already done in fused front)
    gcn_agg32v_kernel<<<NN * 8 / 256, 256, 0, stream>>>(rowptr, csr_src, htmp, dinv, b1, h1);

    // layer 2: 32 -> 32
    dense_tile_kernel<32><<<NN / 128, 256, 0, stream>>>(h1, W2, htmp);
    gcn_agg32v_kernel<<<NN * 8 / 256, 256, 0, stream>>>(rowptr, csr_src, htmp, dinv, b2, h2);

    // layer 3: 32 -> 32
    dense_tile_kernel<32><<<NN / 128, 256, 0, stream>>>(h2, W3, htmp);
    gcn_agg32v_kernel<<<NN * 8 / 256, 256, 0, stream>>>(rowptr, csr_src, htmp, dinv, b3, h3);

    // layer 4: 32 -> 1
    dense4_kernel<<<NN / 256, 256, 0, stream>>>(h3, W4, htmp);
    gcn_agg1_kernel<<<NN / 256, 256, 0, stream>>>(rowptr, csr_src, htmp, dinv, b4, h4);

    // fused sort-pool + CNN head
    pool_cnn_kernel<<<NG, 256, 0, stream>>>(h1, h2, h3, h4, starts,
                                            c1w, c1b, c2w, c2b,
                                            l1w, l1b, l2w, l2b, out);
}

// Round 8
// 247.060 us; speedup vs baseline: 1.2258x; 1.1094x over previous
//
#include <hip/hip_runtime.h>
#include <math.h>

#define NN 102400
#define NE 1638400
#define NG 2048
#define KTOP 30
#define NBUCK 400   // coarse buckets of 256 nodes (dst >> 8)
#define EPB 4096    // edges per pass-1 block
#define NB1 400     // NE / EPB
#define GPB 2       // graphs per pool block

// ---------- fused front: coarse histogram + dense1 + starts ----------
__global__ __launch_bounds__(256) void fused_front_kernel(
    const int* __restrict__ dst, int* __restrict__ hist1,
    const float* __restrict__ x, const float* __restrict__ W1,
    float* __restrict__ htmp,
    const int* __restrict__ batch, int* __restrict__ starts) {
    __shared__ float Wsh[128 * 32];
    __shared__ int hsh[NBUCK];
    int bid = blockIdx.x;
    int tid = threadIdx.x;

    if (bid < NB1) {
        for (int q = tid; q < NBUCK; q += 256) hsh[q] = 0;
        __syncthreads();
        const int4* dp = (const int4*)(dst + bid * EPB);
        for (int i4 = tid; i4 < EPB / 4; i4 += 256) {
            int4 dd = dp[i4];
            atomicAdd(&hsh[dd.x >> 8], 1);
            atomicAdd(&hsh[dd.y >> 8], 1);
            atomicAdd(&hsh[dd.z >> 8], 1);
            atomicAdd(&hsh[dd.w >> 8], 1);
        }
        __syncthreads();
        for (int q = tid; q < NBUCK; q += 256) hist1[q * NB1 + bid] = hsh[q];
    } else if (bid < NB1 + 800) {
        int bidx = bid - NB1;
        for (int i = tid; i < 128 * 32; i += 256) Wsh[i] = W1[i];
        __syncthreads();
        int jb = (tid >> 6) << 3;
        int q = tid & 63;
        int n0 = bidx * 128 + q;
        int n1 = n0 + 64;
        const float* x0p = x + (size_t)n0 * 128;
        const float* x1p = x + (size_t)n1 * 128;
        float acc0[8], acc1[8];
#pragma unroll
        for (int j = 0; j < 8; ++j) { acc0[j] = 0.f; acc1[j] = 0.f; }
#pragma unroll 2
        for (int k = 0; k < 128; k += 4) {
            float4 xa = *(const float4*)(x0p + k);
            float4 xb = *(const float4*)(x1p + k);
            float xs0[4] = {xa.x, xa.y, xa.z, xa.w};
            float xs1[4] = {xb.x, xb.y, xb.z, xb.w};
#pragma unroll
            for (int kk = 0; kk < 4; ++kk) {
                float4 wlo = *(const float4*)&Wsh[(k + kk) * 32 + jb];
                float4 whi = *(const float4*)&Wsh[(k + kk) * 32 + jb + 4];
                float v0 = xs0[kk], v1 = xs1[kk];
                acc0[0] += v0 * wlo.x; acc0[1] += v0 * wlo.y;
                acc0[2] += v0 * wlo.z; acc0[3] += v0 * wlo.w;
                acc0[4] += v0 * whi.x; acc0[5] += v0 * whi.y;
                acc0[6] += v0 * whi.z; acc0[7] += v0 * whi.w;
                acc1[0] += v1 * wlo.x; acc1[1] += v1 * wlo.y;
                acc1[2] += v1 * wlo.z; acc1[3] += v1 * wlo.w;
                acc1[4] += v1 * whi.x; acc1[5] += v1 * whi.y;
                acc1[6] += v1 * whi.z; acc1[7] += v1 * whi.w;
            }
        }
        float4 o0 = {acc0[0], acc0[1], acc0[2], acc0[3]};
        float4 o1 = {acc0[4], acc0[5], acc0[6], acc0[7]};
        float4 o2 = {acc1[0], acc1[1], acc1[2], acc1[3]};
        float4 o3 = {acc1[4], acc1[5], acc1[6], acc1[7]};
        *(float4*)&htmp[(size_t)n0 * 32 + jb] = o0;
        *(float4*)&htmp[(size_t)n0 * 32 + jb + 4] = o1;
        *(float4*)&htmp[(size_t)n1 * 32 + jb] = o2;
        *(float4*)&htmp[(size_t)n1 * 32 + jb + 4] = o3;
    } else {
        int i = (bid - NB1 - 800) * 256 + tid;
        if (i < NN) {
            int c = batch[i];
            int p = (i == 0) ? -1 : batch[i - 1];
            for (int g = p + 1; g <= c; ++g) starts[g] = i;
            if (i == NN - 1) {
                for (int g = c + 1; g <= NG; ++g) starts[g] = NN;
            }
        }
    }
}

// ---------- S1a ----------
__global__ __launch_bounds__(256) void s1a_kernel(const int* __restrict__ hist1,
                                                  int* __restrict__ offs,
                                                  int* __restrict__ totals) {
    __shared__ int A[512], B[512];
    int q = blockIdx.x, tid = threadIdx.x;
    int i0 = tid, i1 = tid + 256;
    int v0 = (i0 < NB1) ? hist1[q * NB1 + i0] : 0;
    int v1 = (i1 < NB1) ? hist1[q * NB1 + i1] : 0;
    A[i0] = v0; A[i1] = v1;
    __syncthreads();
    int* cur = A; int* nxt = B;
    for (int off = 1; off < 512; off <<= 1) {
        nxt[i0] = cur[i0] + ((i0 >= off) ? cur[i0 - off] : 0);
        nxt[i1] = cur[i1] + cur[i1 - off];
        __syncthreads();
        int* t = cur; cur = nxt; nxt = t;
    }
    if (i0 < NB1) offs[q * NB1 + i0] = cur[i0] - v0;
    if (i1 < NB1) offs[q * NB1 + i1] = cur[i1] - v1;
    if (tid == 0) totals[q] = cur[511];
}

// ---------- S1b ----------
__global__ __launch_bounds__(256) void s1b_kernel(const int* __restrict__ totals,
                                                  int* __restrict__ bucketStart,
                                                  int* __restrict__ rowptr) {
    __shared__ int A[512], B[512];
    int tid = threadIdx.x;
    int i0 = tid, i1 = tid + 256;
    int v0 = (i0 < NBUCK) ? totals[i0] : 0;
    int v1 = (i1 < NBUCK) ? totals[i1] : 0;
    A[i0] = v0; A[i1] = v1;
    __syncthreads();
    int* cur = A; int* nxt = B;
    for (int off = 1; off < 512; off <<= 1) {
        nxt[i0] = cur[i0] + ((i0 >= off) ? cur[i0 - off] : 0);
        nxt[i1] = cur[i1] + cur[i1 - off];
        __syncthreads();
        int* t = cur; cur = nxt; nxt = t;
    }
    if (i0 < NBUCK) bucketStart[i0] = cur[i0] - v0;
    if (i1 < NBUCK) bucketStart[i1] = cur[i1] - v1;
    if (tid == 0) { bucketStart[NBUCK] = cur[511]; rowptr[NN] = cur[511]; }
}

// ---------- P1 ----------
__global__ __launch_bounds__(256) void p1_kernel(const int* __restrict__ src,
                                                 const int* __restrict__ dst,
                                                 const int* __restrict__ offs,
                                                 const int* __restrict__ bucketStart,
                                                 unsigned int* __restrict__ ebuf) {
    __shared__ int myoff[NBUCK];
    int b = blockIdx.x, tid = threadIdx.x;
    for (int q = tid; q < NBUCK; q += 256)
        myoff[q] = bucketStart[q] + offs[q * NB1 + b];
    __syncthreads();
    const int4* dp = (const int4*)(dst + b * EPB);
    const int4* sp = (const int4*)(src + b * EPB);
    for (int i4 = tid; i4 < EPB / 4; i4 += 256) {
        int4 dd = dp[i4];
        int4 ss = sp[i4];
        int p0 = atomicAdd(&myoff[dd.x >> 8], 1);
        int p1 = atomicAdd(&myoff[dd.y >> 8], 1);
        int p2 = atomicAdd(&myoff[dd.z >> 8], 1);
        int p3 = atomicAdd(&myoff[dd.w >> 8], 1);
        ebuf[p0] = ((unsigned int)(dd.x & 255) << 24) | (unsigned int)ss.x;
        ebuf[p1] = ((unsigned int)(dd.y & 255) << 24) | (unsigned int)ss.y;
        ebuf[p2] = ((unsigned int)(dd.z & 255) << 24) | (unsigned int)ss.z;
        ebuf[p3] = ((unsigned int)(dd.w & 255) << 24) | (unsigned int)ss.w;
    }
}

// ---------- P2 ----------
__global__ __launch_bounds__(256) void p2_kernel(const unsigned int* __restrict__ ebuf,
                                                 const int* __restrict__ bucketStart,
                                                 int* __restrict__ csr_src,
                                                 int* __restrict__ rowptr,
                                                 float* __restrict__ dinv) {
    __shared__ int fcnt[256];
    __shared__ int tmp[256];
    __shared__ int foff[256];
    int q = blockIdx.x, tid = threadIdx.x;
    int base = bucketStart[q];
    int ecnt = bucketStart[q + 1] - base;
    fcnt[tid] = 0;
    __syncthreads();
    for (int i = tid; i < ecnt; i += 256) {
        unsigned int e = ebuf[base + i];
        atomicAdd(&fcnt[e >> 24], 1);
    }
    __syncthreads();
    int c = fcnt[tid];
    int n = q * 256 + tid;
    dinv[n] = rsqrtf((float)c + 1.0f);
    tmp[tid] = c;
    __syncthreads();
    for (int off = 1; off < 256; off <<= 1) {
        int u = (tid >= off) ? tmp[tid - off] : 0;
        __syncthreads();
        tmp[tid] += u;
        __syncthreads();
    }
    int excl = base + tmp[tid] - c;
    rowptr[n] = excl;
    foff[tid] = excl;
    __syncthreads();
    for (int i = tid; i < ecnt; i += 256) {
        unsigned int e = ebuf[base + i];
        int pos = atomicAdd(&foff[e >> 24], 1);
        csr_src[pos] = (int)(e & 0xFFFFFF);
    }
}

// ---------- fused gather-aggregate + tanh + NEXT-layer dense epilogue ----------
// 32 nodes x 8 lanes per block. Gather loop identical (bit-exact) to before.
// Epilogue: Hs[32][36] LDS tile of the block's output rows, then
// htn = Hs @ Wn with k-ascending accumulation (same order as dense_tile).

template <int NEXT>  // 32 (-> full 32x32 dense) or 1 (-> 32->1 dense)
__global__ __launch_bounds__(256) void gcn_aggd_kernel(
    const int* __restrict__ rowptr, const int* __restrict__ csr_src,
    const float* __restrict__ htmp, const float* __restrict__ dinv,
    const float* __restrict__ b, const float* __restrict__ Wn,
    float* __restrict__ hout, float* __restrict__ htn) {
    __shared__ float Ws[32 * 32];
    __shared__ float Hs[32][36];
    int tid = threadIdx.x;
    if (NEXT == 32) {
        for (int i = tid; i < 1024; i += 256) Ws[i] = Wn[i];
    } else {
        if (tid < 32) Ws[tid] = Wn[tid];
    }
    int idx = blockIdx.x * 256 + tid;
    int n = idx >> 3, fg = (idx & 7) << 2;
    int beg = rowptr[n], end = rowptr[n + 1];
    float di = dinv[n];
    float4 acc = {0.f, 0.f, 0.f, 0.f};
    int i = beg;
    for (; i + 7 < end; i += 8) {
        int s[8];
#pragma unroll
        for (int k = 0; k < 8; ++k) s[k] = csr_src[i + k];
        float c[8];
#pragma unroll
        for (int k = 0; k < 8; ++k) c[k] = dinv[s[k]] * di;
        float4 v[8];
#pragma unroll
        for (int k = 0; k < 8; ++k) v[k] = *(const float4*)&htmp[(size_t)s[k] * 32 + fg];
#pragma unroll
        for (int k = 0; k < 8; ++k) {
            acc.x += v[k].x * c[k]; acc.y += v[k].y * c[k];
            acc.z += v[k].z * c[k]; acc.w += v[k].w * c[k];
        }
    }
    for (; i + 3 < end; i += 4) {
        int s0 = csr_src[i], s1 = csr_src[i + 1];
        int s2 = csr_src[i + 2], s3 = csr_src[i + 3];
        float c0 = dinv[s0] * di, c1 = dinv[s1] * di;
        float c2 = dinv[s2] * di, c3 = dinv[s3] * di;
        float4 v0 = *(const float4*)&htmp[(size_t)s0 * 32 + fg];
        float4 v1 = *(const float4*)&htmp[(size_t)s1 * 32 + fg];
        float4 v2 = *(const float4*)&htmp[(size_t)s2 * 32 + fg];
        float4 v3 = *(const float4*)&htmp[(size_t)s3 * 32 + fg];
        acc.x += v0.x * c0; acc.y += v0.y * c0; acc.z += v0.z * c0; acc.w += v0.w * c0;
        acc.x += v1.x * c1; acc.y += v1.y * c1; acc.z += v1.z * c1; acc.w += v1.w * c1;
        acc.x += v2.x * c2; acc.y += v2.y * c2; acc.z += v2.z * c2; acc.w += v2.w * c2;
        acc.x += v3.x * c3; acc.y += v3.y * c3; acc.z += v3.z * c3; acc.w += v3.w * c3;
    }
    for (; i < end; ++i) {
        int s = csr_src[i];
        float c = dinv[s] * di;
        float4 v = *(const float4*)&htmp[(size_t)s * 32 + fg];
        acc.x += v.x * c; acc.y += v.y * c; acc.z += v.z * c; acc.w += v.w * c;
    }
    float dd = di * di;
    float4 hs = *(const float4*)&htmp[(size_t)n * 32 + fg];
    float4 bb = *(const float4*)&b[fg];
    float4 o;
    o.x = tanhf(acc.x + hs.x * dd + bb.x);
    o.y = tanhf(acc.y + hs.y * dd + bb.y);
    o.z = tanhf(acc.z + hs.z * dd + bb.z);
    o.w = tanhf(acc.w + hs.w * dd + bb.w);
    *(float4*)&hout[(size_t)n * 32 + fg] = o;
    int nl = tid >> 3;
    *(float4*)&Hs[nl][fg] = o;
    __syncthreads();
    if (NEXT == 32) {
        int n2 = tid >> 3, j4 = (tid & 7) << 2;
        int gnode = blockIdx.x * 32 + n2;
        float4 r = {0.f, 0.f, 0.f, 0.f};
#pragma unroll
        for (int k = 0; k < 32; ++k) {
            float h = Hs[n2][k];
            float4 wv = *(const float4*)&Ws[k * 32 + j4];
            r.x += h * wv.x; r.y += h * wv.y; r.z += h * wv.z; r.w += h * wv.w;
        }
        *(float4*)&htn[(size_t)gnode * 32 + j4] = r;
    } else {
        if (tid < 32) {
            int gnode = blockIdx.x * 32 + tid;
            float s = 0.f;
#pragma unroll
            for (int k = 0; k < 32; ++k) s += Hs[tid][k] * Ws[k];
            htn[gnode] = s;
        }
    }
}

__global__ __launch_bounds__(256) void gcn_agg1_kernel(
    const int* __restrict__ rowptr, const int* __restrict__ csr_src,
    const float* __restrict__ htmp, const float* __restrict__ dinv,
    const float* __restrict__ b, float* __restrict__ hout) {
    int n = blockIdx.x * blockDim.x + threadIdx.x;
    if (n >= NN) return;
    int beg = rowptr[n], end = rowptr[n + 1];
    float di = dinv[n];
    float acc = 0.f;
    int i = beg;
    for (; i + 7 < end; i += 8) {
        int s[8];
#pragma unroll
        for (int k = 0; k < 8; ++k) s[k] = csr_src[i + k];
        float c[8], v[8];
#pragma unroll
        for (int k = 0; k < 8; ++k) c[k] = dinv[s[k]] * di;
#pragma unroll
        for (int k = 0; k < 8; ++k) v[k] = htmp[s[k]];
#pragma unroll
        for (int k = 0; k < 8; ++k) acc += v[k] * c[k];
    }
    for (; i < end; ++i) {
        int s = csr_src[i];
        acc += htmp[s] * (dinv[s] * di);
    }
    hout[n] = tanhf(acc + htmp[n] * di * di + b[0]);
}

// ---------- sort-pool + CNN head: 2 graphs per block ----------

__global__ __launch_bounds__(256) void pool_cnn_kernel(
    const float* __restrict__ h1, const float* __restrict__ h2,
    const float* __restrict__ h3, const float* __restrict__ h4,
    const int* __restrict__ starts,
    const float* __restrict__ c1w, const float* __restrict__ c1b,
    const float* __restrict__ c2w, const float* __restrict__ c2b,
    const float* __restrict__ l1w, const float* __restrict__ l1b,
    const float* __restrict__ l2w, const float* __restrict__ l2b,
    float* __restrict__ out) {
    __shared__ float Psh[GPB * 3000];   // per-graph P[30][100]; aliased y2/y3/z after conv1
    __shared__ float CW[16 * 100];      // staged c1w, shared by both graphs
    __shared__ float KY[GPB * 480];     // per-graph keys (<=480) ∪ y1[16][30]
    int tid = threadIdx.x;
    int gg = tid >> 7;        // 0/1
    int lt = tid & 127;
    int g = blockIdx.x * GPB + gg;
    float* P  = Psh + gg * 3000;
    float* ky = KY + gg * 480;
    float* y2 = P;
    float* y3 = P + 240;
    float* z  = P + 592;

    int start = starts[g];
    int end = starts[g + 1];
    int cnt = end - start;

    for (int i = lt; i < 3000; i += 128) P[i] = 0.f;
    for (int i = tid; i < 16 * 97; i += 256) {
        int c = i / 97, f = i % 97;
        CW[c * 100 + f] = c1w[i];
    }
    bool fits = (cnt <= 480);
    if (fits) {
        for (int i = lt; i < cnt; i += 128) ky[i] = h4[start + i];
    }
    __syncthreads();

    for (int i = lt; i < cnt; i += 128) {
        float key = fits ? ky[i] : h4[start + i];
        int rank = 0;
        if (fits) {
            for (int j = 0; j < cnt; ++j) {
                float kj = ky[j];
                rank += (kj > key) || (kj == key && j < i);
            }
        } else {
            for (int j = 0; j < cnt; ++j) {
                float kj = h4[start + j];
                rank += (kj > key) || (kj == key && j < i);
            }
        }
        if (rank < KTOP) {
            int node = start + i;
            const float4* r1 = (const float4*)(h1 + (size_t)node * 32);
            const float4* r2 = (const float4*)(h2 + (size_t)node * 32);
            const float4* r3 = (const float4*)(h3 + (size_t)node * 32);
            float* Pr = P + rank * 100;
#pragma unroll
            for (int q = 0; q < 8; ++q) *(float4*)&Pr[4 * q] = r1[q];
#pragma unroll
            for (int q = 0; q < 8; ++q) *(float4*)&Pr[32 + 4 * q] = r2[q];
#pragma unroll
            for (int q = 0; q < 8; ++q) *(float4*)&Pr[64 + 4 * q] = r3[q];
            Pr[96] = key;
        }
    }
    __syncthreads();

    // conv1: t=o>>4 mapping (4 distinct P rows per wave); f ascending -> bit-exact.
    for (int o = lt; o < 16 * KTOP; o += 128) {
        int t = o >> 4, c = o & 15;
        float s = c1b[c];
        const float* Pr = P + t * 100;
        const float* Wr = &CW[c * 100];
#pragma unroll
        for (int f4 = 0; f4 < 24; ++f4) {
            float4 pv = *(const float4*)(Pr + 4 * f4);
            float4 wv = *(const float4*)(Wr + 4 * f4);
            s += wv.x * pv.x; s += wv.y * pv.y; s += wv.z * pv.z; s += wv.w * pv.w;
        }
        s += Wr[96] * Pr[96];
        ky[c * KTOP + t] = fmaxf(s, 0.f);   // y1 (keys dead)
    }
    __syncthreads();

    for (int o = lt; o < 16 * 15; o += 128) {
        int c = o / 15, t = o % 15;
        y2[o] = fmaxf(ky[c * KTOP + 2 * t], ky[c * KTOP + 2 * t + 1]);
    }
    __syncthreads();

    for (int o = lt; o < 32 * 11; o += 128) {
        int c = o / 11, t = o % 11;
        float s = c2b[c];
#pragma unroll
        for (int i = 0; i < 16; ++i)
#pragma unroll
            for (int j = 0; j < 5; ++j)
                s += c2w[(c * 16 + i) * 5 + j] * y2[i * 15 + t + j];
        y3[o] = fmaxf(s, 0.f);
    }
    __syncthreads();

    // l1: all 128 threads/graph active, coalesced stride-128 weight loads.
    {
        int o = lt;
        float s = l1b[o];
#pragma unroll 16
        for (int i = 0; i < 352; ++i) s += y3[i] * l1w[i * 128 + o];
        z[o] = fmaxf(s, 0.f);
    }
    __syncthreads();

    if (lt == 0) {
        float s = l2b[0];
#pragma unroll 4
        for (int i = 0; i < 128; ++i) s += z[i] * l2w[i];
        out[g] = 1.f / (1.f + expf(-s));
    }
}

extern "C" void kernel_launch(void* const* d_in, const int* in_sizes, int n_in,
                              void* d_out, int out_size, void* d_ws, size_t ws_size,
                              hipStream_t stream) {
    const float* x   = (const float*)d_in[0];
    const int* ei    = (const int*)d_in[1];
    const int* batch = (const int*)d_in[2];
    const float* W1  = (const float*)d_in[3];
    const float* b1  = (const float*)d_in[4];
    const float* W2  = (const float*)d_in[5];
    const float* b2  = (const float*)d_in[6];
    const float* W3  = (const float*)d_in[7];
    const float* b3  = (const float*)d_in[8];
    const float* W4  = (const float*)d_in[9];
    const float* b4  = (const float*)d_in[10];
    const float* c1w = (const float*)d_in[11];
    const float* c1b = (const float*)d_in[12];
    const float* c2w = (const float*)d_in[13];
    const float* c2b = (const float*)d_in[14];
    const float* l1w = (const float*)d_in[15];
    const float* l1b = (const float*)d_in[16];
    const float* l2w = (const float*)d_in[17];
    const float* l2b = (const float*)d_in[18];
    float* out = (float*)d_out;

    const int* srcp = ei;
    const int* dstp = ei + NE;

    // workspace layout
    char* w = (char*)d_ws;
    float* dinv      = (float*)w;               w += sizeof(float) * NN;
    float* htmpA     = (float*)w;               w += sizeof(float) * NN * 32;
    float* htmpB     = (float*)w;               w += sizeof(float) * NN * 32;
    float* h1        = (float*)w;               w += sizeof(float) * NN * 32;
    float* h2        = (float*)w;               w += sizeof(float) * NN * 32;  // ebuf aliases here
    float* h3        = (float*)w;               w += sizeof(float) * NN * 32;
    float* h4        = (float*)w;               w += sizeof(float) * NN;
    int*   rowptr    = (int*)w;                 w += sizeof(int) * (NN + 1);
    int*   hist1     = (int*)w;                 w += sizeof(int) * NBUCK * NB1;
    int*   offs      = (int*)w;                 w += sizeof(int) * NBUCK * NB1;
    int*   totals    = (int*)w;                 w += sizeof(int) * NBUCK;
    int*   bucketStart = (int*)w;               w += sizeof(int) * (NBUCK + 1);
    int*   csr_src   = (int*)w;                 w += sizeof(int) * NE;
    int*   starts    = (int*)w;                 w += sizeof(int) * (NG + 1);

    // ebuf (6.55 MB) aliases h2 (13.1 MB): h2 is first written by agg layer 2,
    // long after p2 has consumed ebuf.
    unsigned int* ebuf = (unsigned int*)h2;

    // CSR build (no global atomics) + dense1 + starts
    fused_front_kernel<<<NB1 + 800 + 400, 256, 0, stream>>>(dstp, hist1, x, W1, htmpA,
                                                            batch, starts);
    s1a_kernel<<<NBUCK, 256, 0, stream>>>(hist1, offs, totals);
    s1b_kernel<<<1, 256, 0, stream>>>(totals, bucketStart, rowptr);
    p1_kernel<<<NB1, 256, 0, stream>>>(srcp, dstp, offs, bucketStart, ebuf);
    p2_kernel<<<NBUCK, 256, 0, stream>>>(ebuf, bucketStart, csr_src, rowptr, dinv);

    // layer 1 agg (+ fused dense W2): htmpA -> h1, htmpB
    gcn_aggd_kernel<32><<<NN / 32, 256, 0, stream>>>(rowptr, csr_src, htmpA, dinv, b1,
                                                     W2, h1, htmpB);
    // layer 2 agg (+ fused dense W3): htmpB -> h2, htmpA
    gcn_aggd_kernel<32><<<NN / 32, 256, 0, stream>>>(rowptr, csr_src, htmpB, dinv, b2,
                                                     W3, h2, htmpA);
    // layer 3 agg (+ fused dense W4 32->1): htmpA -> h3, htmpB[0:NN]
    gcn_aggd_kernel<1><<<NN / 32, 256, 0, stream>>>(rowptr, csr_src, htmpA, dinv, b3,
                                                    W4, h3, htmpB);
    // layer 4 agg: htmpB[0:NN] -> h4
    gcn_agg1_kernel<<<NN / 256, 256, 0, stream>>>(rowptr, csr_src, htmpB, dinv, b4, h4);

    // fused sort-pool + CNN head, 2 graphs per block
    pool_cnn_kernel<<<NG / GPB, 256, 0, stream>>>(h1, h2, h3, h4, starts,
                                                  c1w, c1b, c2w, c2b,
                                                  l1w, l1b, l2w, l2b, out);
}

// Round 9
// 243.996 us; speedup vs baseline: 1.2412x; 1.0126x over previous
//
#include <hip/hip_runtime.h>
#include <math.h>

#define NN 102400
#define NE 1638400
#define NG 2048
#define KTOP 30
#define NBUCK 400   // coarse buckets of 256 nodes (dst >> 8)
#define EPB 4096    // edges per pass-1 block
#define NB1 400     // NE / EPB

// ---------- fused front: coarse histogram + dense1 + starts ----------
__global__ __launch_bounds__(256) void fused_front_kernel(
    const int* __restrict__ dst, int* __restrict__ hist1,
    const float* __restrict__ x, const float* __restrict__ W1,
    float* __restrict__ htmp,
    const int* __restrict__ batch, int* __restrict__ starts) {
    __shared__ float Wsh[128 * 32];
    __shared__ int hsh[NBUCK];
    int bid = blockIdx.x;
    int tid = threadIdx.x;

    if (bid < NB1) {
        for (int q = tid; q < NBUCK; q += 256) hsh[q] = 0;
        __syncthreads();
        const int4* dp = (const int4*)(dst + bid * EPB);
        for (int i4 = tid; i4 < EPB / 4; i4 += 256) {
            int4 dd = dp[i4];
            atomicAdd(&hsh[dd.x >> 8], 1);
            atomicAdd(&hsh[dd.y >> 8], 1);
            atomicAdd(&hsh[dd.z >> 8], 1);
            atomicAdd(&hsh[dd.w >> 8], 1);
        }
        __syncthreads();
        for (int q = tid; q < NBUCK; q += 256) hist1[q * NB1 + bid] = hsh[q];
    } else if (bid < NB1 + 800) {
        int bidx = bid - NB1;
        for (int i = tid; i < 128 * 32; i += 256) Wsh[i] = W1[i];
        __syncthreads();
        int jb = (tid >> 6) << 3;
        int q = tid & 63;
        int n0 = bidx * 128 + q;
        int n1 = n0 + 64;
        const float* x0p = x + (size_t)n0 * 128;
        const float* x1p = x + (size_t)n1 * 128;
        float acc0[8], acc1[8];
#pragma unroll
        for (int j = 0; j < 8; ++j) { acc0[j] = 0.f; acc1[j] = 0.f; }
#pragma unroll 2
        for (int k = 0; k < 128; k += 4) {
            float4 xa = *(const float4*)(x0p + k);
            float4 xb = *(const float4*)(x1p + k);
            float xs0[4] = {xa.x, xa.y, xa.z, xa.w};
            float xs1[4] = {xb.x, xb.y, xb.z, xb.w};
#pragma unroll
            for (int kk = 0; kk < 4; ++kk) {
                float4 wlo = *(const float4*)&Wsh[(k + kk) * 32 + jb];
                float4 whi = *(const float4*)&Wsh[(k + kk) * 32 + jb + 4];
                float v0 = xs0[kk], v1 = xs1[kk];
                acc0[0] += v0 * wlo.x; acc0[1] += v0 * wlo.y;
                acc0[2] += v0 * wlo.z; acc0[3] += v0 * wlo.w;
                acc0[4] += v0 * whi.x; acc0[5] += v0 * whi.y;
                acc0[6] += v0 * whi.z; acc0[7] += v0 * whi.w;
                acc1[0] += v1 * wlo.x; acc1[1] += v1 * wlo.y;
                acc1[2] += v1 * wlo.z; acc1[3] += v1 * wlo.w;
                acc1[4] += v1 * whi.x; acc1[5] += v1 * whi.y;
                acc1[6] += v1 * whi.z; acc1[7] += v1 * whi.w;
            }
        }
        float4 o0 = {acc0[0], acc0[1], acc0[2], acc0[3]};
        float4 o1 = {acc0[4], acc0[5], acc0[6], acc0[7]};
        float4 o2 = {acc1[0], acc1[1], acc1[2], acc1[3]};
        float4 o3 = {acc1[4], acc1[5], acc1[6], acc1[7]};
        *(float4*)&htmp[(size_t)n0 * 32 + jb] = o0;
        *(float4*)&htmp[(size_t)n0 * 32 + jb + 4] = o1;
        *(float4*)&htmp[(size_t)n1 * 32 + jb] = o2;
        *(float4*)&htmp[(size_t)n1 * 32 + jb + 4] = o3;
    } else {
        int i = (bid - NB1 - 800) * 256 + tid;
        if (i < NN) {
            int c = batch[i];
            int p = (i == 0) ? -1 : batch[i - 1];
            for (int g = p + 1; g <= c; ++g) starts[g] = i;
            if (i == NN - 1) {
                for (int g = c + 1; g <= NG; ++g) starts[g] = NN;
            }
        }
    }
}

// ---------- S1a ----------
__global__ __launch_bounds__(256) void s1a_kernel(const int* __restrict__ hist1,
                                                  int* __restrict__ offs,
                                                  int* __restrict__ totals) {
    __shared__ int A[512], B[512];
    int q = blockIdx.x, tid = threadIdx.x;
    int i0 = tid, i1 = tid + 256;
    int v0 = (i0 < NB1) ? hist1[q * NB1 + i0] : 0;
    int v1 = (i1 < NB1) ? hist1[q * NB1 + i1] : 0;
    A[i0] = v0; A[i1] = v1;
    __syncthreads();
    int* cur = A; int* nxt = B;
    for (int off = 1; off < 512; off <<= 1) {
        nxt[i0] = cur[i0] + ((i0 >= off) ? cur[i0 - off] : 0);
        nxt[i1] = cur[i1] + cur[i1 - off];
        __syncthreads();
        int* t = cur; cur = nxt; nxt = t;
    }
    if (i0 < NB1) offs[q * NB1 + i0] = cur[i0] - v0;
    if (i1 < NB1) offs[q * NB1 + i1] = cur[i1] - v1;
    if (tid == 0) totals[q] = cur[511];
}

// ---------- S1b ----------
__global__ __launch_bounds__(256) void s1b_kernel(const int* __restrict__ totals,
                                                  int* __restrict__ bucketStart,
                                                  int* __restrict__ rowptr) {
    __shared__ int A[512], B[512];
    int tid = threadIdx.x;
    int i0 = tid, i1 = tid + 256;
    int v0 = (i0 < NBUCK) ? totals[i0] : 0;
    int v1 = (i1 < NBUCK) ? totals[i1] : 0;
    A[i0] = v0; A[i1] = v1;
    __syncthreads();
    int* cur = A; int* nxt = B;
    for (int off = 1; off < 512; off <<= 1) {
        nxt[i0] = cur[i0] + ((i0 >= off) ? cur[i0 - off] : 0);
        nxt[i1] = cur[i1] + cur[i1 - off];
        __syncthreads();
        int* t = cur; cur = nxt; nxt = t;
    }
    if (i0 < NBUCK) bucketStart[i0] = cur[i0] - v0;
    if (i1 < NBUCK) bucketStart[i1] = cur[i1] - v1;
    if (tid == 0) { bucketStart[NBUCK] = cur[511]; rowptr[NN] = cur[511]; }
}

// ---------- P1 ----------
__global__ __launch_bounds__(256) void p1_kernel(const int* __restrict__ src,
                                                 const int* __restrict__ dst,
                                                 const int* __restrict__ offs,
                                                 const int* __restrict__ bucketStart,
                                                 unsigned int* __restrict__ ebuf) {
    __shared__ int myoff[NBUCK];
    int b = blockIdx.x, tid = threadIdx.x;
    for (int q = tid; q < NBUCK; q += 256)
        myoff[q] = bucketStart[q] + offs[q * NB1 + b];
    __syncthreads();
    const int4* dp = (const int4*)(dst + b * EPB);
    const int4* sp = (const int4*)(src + b * EPB);
    for (int i4 = tid; i4 < EPB / 4; i4 += 256) {
        int4 dd = dp[i4];
        int4 ss = sp[i4];
        int p0 = atomicAdd(&myoff[dd.x >> 8], 1);
        int p1 = atomicAdd(&myoff[dd.y >> 8], 1);
        int p2 = atomicAdd(&myoff[dd.z >> 8], 1);
        int p3 = atomicAdd(&myoff[dd.w >> 8], 1);
        ebuf[p0] = ((unsigned int)(dd.x & 255) << 24) | (unsigned int)ss.x;
        ebuf[p1] = ((unsigned int)(dd.y & 255) << 24) | (unsigned int)ss.y;
        ebuf[p2] = ((unsigned int)(dd.z & 255) << 24) | (unsigned int)ss.z;
        ebuf[p3] = ((unsigned int)(dd.w & 255) << 24) | (unsigned int)ss.w;
    }
}

// ---------- P2 ----------
__global__ __launch_bounds__(256) void p2_kernel(const unsigned int* __restrict__ ebuf,
                                                 const int* __restrict__ bucketStart,
                                                 int* __restrict__ csr_src,
                                                 int* __restrict__ rowptr,
                                                 float* __restrict__ dinv) {
    __shared__ int fcnt[256];
    __shared__ int tmp[256];
    __shared__ int foff[256];
    int q = blockIdx.x, tid = threadIdx.x;
    int base = bucketStart[q];
    int ecnt = bucketStart[q + 1] - base;
    fcnt[tid] = 0;
    __syncthreads();
    for (int i = tid; i < ecnt; i += 256) {
        unsigned int e = ebuf[base + i];
        atomicAdd(&fcnt[e >> 24], 1);
    }
    __syncthreads();
    int c = fcnt[tid];
    int n = q * 256 + tid;
    dinv[n] = rsqrtf((float)c + 1.0f);
    tmp[tid] = c;
    __syncthreads();
    for (int off = 1; off < 256; off <<= 1) {
        int u = (tid >= off) ? tmp[tid - off] : 0;
        __syncthreads();
        tmp[tid] += u;
        __syncthreads();
    }
    int excl = base + tmp[tid] - c;
    rowptr[n] = excl;
    foff[tid] = excl;
    __syncthreads();
    for (int i = tid; i < ecnt; i += 256) {
        unsigned int e = ebuf[base + i];
        int pos = atomicAdd(&foff[e >> 24], 1);
        csr_src[pos] = (int)(e & 0xFFFFFF);
    }
}

// ---------- fused gather-aggregate + tanh + NEXT-layer dense epilogue ----------
template <int NEXT>  // 32 (-> full 32x32 dense) or 1 (-> 32->1 dense)
__global__ __launch_bounds__(256) void gcn_aggd_kernel(
    const int* __restrict__ rowptr, const int* __restrict__ csr_src,
    const float* __restrict__ htmp, const float* __restrict__ dinv,
    const float* __restrict__ b, const float* __restrict__ Wn,
    float* __restrict__ hout, float* __restrict__ htn) {
    __shared__ float Ws[32 * 32];
    __shared__ float Hs[32][36];
    int tid = threadIdx.x;
    if (NEXT == 32) {
        for (int i = tid; i < 1024; i += 256) Ws[i] = Wn[i];
    } else {
        if (tid < 32) Ws[tid] = Wn[tid];
    }
    int idx = blockIdx.x * 256 + tid;
    int n = idx >> 3, fg = (idx & 7) << 2;
    int beg = rowptr[n], end = rowptr[n + 1];
    float di = dinv[n];
    float4 acc = {0.f, 0.f, 0.f, 0.f};
    int i = beg;
    for (; i + 7 < end; i += 8) {
        int s[8];
#pragma unroll
        for (int k = 0; k < 8; ++k) s[k] = csr_src[i + k];
        float c[8];
#pragma unroll
        for (int k = 0; k < 8; ++k) c[k] = dinv[s[k]] * di;
        float4 v[8];
#pragma unroll
        for (int k = 0; k < 8; ++k) v[k] = *(const float4*)&htmp[(size_t)s[k] * 32 + fg];
#pragma unroll
        for (int k = 0; k < 8; ++k) {
            acc.x += v[k].x * c[k]; acc.y += v[k].y * c[k];
            acc.z += v[k].z * c[k]; acc.w += v[k].w * c[k];
        }
    }
    for (; i + 3 < end; i += 4) {
        int s0 = csr_src[i], s1 = csr_src[i + 1];
        int s2 = csr_src[i + 2], s3 = csr_src[i + 3];
        float c0 = dinv[s0] * di, c1 = dinv[s1] * di;
        float c2 = dinv[s2] * di, c3 = dinv[s3] * di;
        float4 v0 = *(const float4*)&htmp[(size_t)s0 * 32 + fg];
        float4 v1 = *(const float4*)&htmp[(size_t)s1 * 32 + fg];
        float4 v2 = *(const float4*)&htmp[(size_t)s2 * 32 + fg];
        float4 v3 = *(const float4*)&htmp[(size_t)s3 * 32 + fg];
        acc.x += v0.x * c0; acc.y += v0.y * c0; acc.z += v0.z * c0; acc.w += v0.w * c0;
        acc.x += v1.x * c1; acc.y += v1.y * c1; acc.z += v1.z * c1; acc.w += v1.w * c1;
        acc.x += v2.x * c2; acc.y += v2.y * c2; acc.z += v2.z * c2; acc.w += v2.w * c2;
        acc.x += v3.x * c3; acc.y += v3.y * c3; acc.z += v3.z * c3; acc.w += v3.w * c3;
    }
    for (; i < end; ++i) {
        int s = csr_src[i];
        float c = dinv[s] * di;
        float4 v = *(const float4*)&htmp[(size_t)s * 32 + fg];
        acc.x += v.x * c; acc.y += v.y * c; acc.z += v.z * c; acc.w += v.w * c;
    }
    float dd = di * di;
    float4 hs = *(const float4*)&htmp[(size_t)n * 32 + fg];
    float4 bb = *(const float4*)&b[fg];
    float4 o;
    o.x = tanhf(acc.x + hs.x * dd + bb.x);
    o.y = tanhf(acc.y + hs.y * dd + bb.y);
    o.z = tanhf(acc.z + hs.z * dd + bb.z);
    o.w = tanhf(acc.w + hs.w * dd + bb.w);
    *(float4*)&hout[(size_t)n * 32 + fg] = o;
    int nl = tid >> 3;
    *(float4*)&Hs[nl][fg] = o;
    __syncthreads();
    if (NEXT == 32) {
        int n2 = tid >> 3, j4 = (tid & 7) << 2;
        int gnode = blockIdx.x * 32 + n2;
        float4 r = {0.f, 0.f, 0.f, 0.f};
#pragma unroll
        for (int k = 0; k < 32; ++k) {
            float h = Hs[n2][k];
            float4 wv = *(const float4*)&Ws[k * 32 + j4];
            r.x += h * wv.x; r.y += h * wv.y; r.z += h * wv.z; r.w += h * wv.w;
        }
        *(float4*)&htn[(size_t)gnode * 32 + j4] = r;
    } else {
        if (tid < 32) {
            int gnode = blockIdx.x * 32 + tid;
            float s = 0.f;
#pragma unroll
            for (int k = 0; k < 32; ++k) s += Hs[tid][k] * Ws[k];
            htn[gnode] = s;
        }
    }
}

__global__ __launch_bounds__(256) void gcn_agg1_kernel(
    const int* __restrict__ rowptr, const int* __restrict__ csr_src,
    const float* __restrict__ htmp, const float* __restrict__ dinv,
    const float* __restrict__ b, float* __restrict__ hout) {
    int n = blockIdx.x * blockDim.x + threadIdx.x;
    if (n >= NN) return;
    int beg = rowptr[n], end = rowptr[n + 1];
    float di = dinv[n];
    float acc = 0.f;
    int i = beg;
    for (; i + 7 < end; i += 8) {
        int s[8];
#pragma unroll
        for (int k = 0; k < 8; ++k) s[k] = csr_src[i + k];
        float c[8], v[8];
#pragma unroll
        for (int k = 0; k < 8; ++k) c[k] = dinv[s[k]] * di;
#pragma unroll
        for (int k = 0; k < 8; ++k) v[k] = htmp[s[k]];
#pragma unroll
        for (int k = 0; k < 8; ++k) acc += v[k] * c[k];
    }
    for (; i < end; ++i) {
        int s = csr_src[i];
        acc += htmp[s] * (dinv[s] * di);
    }
    hout[n] = tanhf(acc + htmp[n] * di * di + b[0]);
}

// ---------- sort-pool + CNN head: 1 graph/block, cooperative P-fill ----------

#define PSTR 100

__global__ __launch_bounds__(256) void pool_cnn_kernel(
    const float* __restrict__ h1, const float* __restrict__ h2,
    const float* __restrict__ h3, const float* __restrict__ h4,
    const int* __restrict__ starts,
    const float* __restrict__ c1w, const float* __restrict__ c1b,
    const float* __restrict__ c2w, const float* __restrict__ c2b,
    const float* __restrict__ l1w, const float* __restrict__ l1b,
    const float* __restrict__ l2w, const float* __restrict__ l2b,
    float* __restrict__ out) {
    __shared__ float P[KTOP][PSTR];
    __shared__ float CW[16 * PSTR];
    __shared__ float KY[480];
    __shared__ int   sel_node[KTOP];
    __shared__ float sel_key[KTOP];
    float* keys = KY;
    float* y2 = &P[0][0];
    float* y3 = &P[0][0] + 240;
    float* z  = &P[0][0] + 592;
    int g = blockIdx.x;
    int tid = threadIdx.x;

    int start = starts[g];
    int end = starts[g + 1];
    int cnt = end - start;

    for (int i = tid; i < KTOP * PSTR; i += 256) (&P[0][0])[i] = 0.f;
    for (int i = tid; i < 16 * 97; i += 256) {
        int c = i / 97, f = i % 97;
        CW[c * PSTR + f] = c1w[i];
    }
    bool fits = (cnt <= 480);
    if (fits) {
        for (int i = tid; i < cnt; i += 256) keys[i] = h4[start + i];
    }
    __syncthreads();

    // rank; record selection list (ranks are distinct -> no write conflicts)
    for (int i = tid; i < cnt; i += 256) {
        float key = fits ? keys[i] : h4[start + i];
        int rank = 0;
        if (fits) {
            for (int j = 0; j < cnt; ++j) {
                float kj = keys[j];
                rank += (kj > key) || (kj == key && j < i);
            }
        } else {
            for (int j = 0; j < cnt; ++j) {
                float kj = h4[start + j];
                rank += (kj > key) || (kj == key && j < i);
            }
        }
        if (rank < KTOP) {
            sel_node[rank] = start + i;
            sel_key[rank] = key;
        }
    }
    __syncthreads();

    // cooperative P-fill: nsel rows x 24 float4 spread over all 256 threads;
    // threads u..u+7 of a row-cluster read one contiguous 128B line.
    int nsel = (cnt < KTOP) ? cnt : KTOP;
    for (int u = tid; u < nsel * 24; u += 256) {
        int r = u / 24, q = u % 24;
        int node = sel_node[r];
        const float* srcp = (q < 8) ? h1 : (q < 16) ? h2 : h3;
        int qq = q & 7;
        float4 v = *(const float4*)(srcp + (size_t)node * 32 + 4 * qq);
        *(float4*)&P[r][(q < 8 ? 0 : (q < 16 ? 32 : 64)) + 4 * qq] = v;
    }
    for (int r = tid; r < nsel; r += 256) P[r][96] = sel_key[r];
    __syncthreads();

    // conv1: t=o>>4 mapping (4 distinct P rows per wave); f ascending -> bit-exact.
    for (int o = tid; o < 16 * KTOP; o += 256) {
        int t = o >> 4, c = o & 15;
        float s = c1b[c];
        const float* Pr = &P[t][0];
        const float* Wr = &CW[c * PSTR];
#pragma unroll
        for (int f4 = 0; f4 < 24; ++f4) {
            float4 pv = *(const float4*)(Pr + 4 * f4);
            float4 wv = *(const float4*)(Wr + 4 * f4);
            s += wv.x * pv.x; s += wv.y * pv.y; s += wv.z * pv.z; s += wv.w * pv.w;
        }
        s += Wr[96] * Pr[96];
        KY[c * KTOP + t] = fmaxf(s, 0.f);   // y1 (keys dead)
    }
    __syncthreads();

    for (int o = tid; o < 16 * 15; o += 256) {
        int c = o / 15, t = o % 15;
        y2[o] = fmaxf(KY[c * KTOP + 2 * t], KY[c * KTOP + 2 * t + 1]);
    }
    __syncthreads();

    for (int o = tid; o < 32 * 11; o += 256) {
        int c = o / 11, t = o % 11;
        float s = c2b[c];
#pragma unroll
        for (int i = 0; i < 16; ++i)
#pragma unroll
            for (int j = 0; j < 5; ++j)
                s += c2w[(c * 16 + i) * 5 + j] * y2[i * 15 + t + j];
        y3[o] = fmaxf(s, 0.f);
    }
    __syncthreads();

    // l1: coalesced stride-128 weight loads; i ascending -> bit-exact.
    for (int o = tid; o < 128; o += 256) {
        float s = l1b[o];
#pragma unroll 16
        for (int i = 0; i < 352; ++i) s += y3[i] * l1w[i * 128 + o];
        z[o] = fmaxf(s, 0.f);
    }
    __syncthreads();

    if (tid == 0) {
        float s = l2b[0];
#pragma unroll 4
        for (int i = 0; i < 128; ++i) s += z[i] * l2w[i];
        out[g] = 1.f / (1.f + expf(-s));
    }
}

extern "C" void kernel_launch(void* const* d_in, const int* in_sizes, int n_in,
                              void* d_out, int out_size, void* d_ws, size_t ws_size,
                              hipStream_t stream) {
    const float* x   = (const float*)d_in[0];
    const int* ei    = (const int*)d_in[1];
    const int* batch = (const int*)d_in[2];
    const float* W1  = (const float*)d_in[3];
    const float* b1  = (const float*)d_in[4];
    const float* W2  = (const float*)d_in[5];
    const float* b2  = (const float*)d_in[6];
    const float* W3  = (const float*)d_in[7];
    const float* b3  = (const float*)d_in[8];
    const float* W4  = (const float*)d_in[9];
    const float* b4  = (const float*)d_in[10];
    const float* c1w = (const float*)d_in[11];
    const float* c1b = (const float*)d_in[12];
    const float* c2w = (const float*)d_in[13];
    const float* c2b = (const float*)d_in[14];
    const float* l1w = (const float*)d_in[15];
    const float* l1b = (const float*)d_in[16];
    const float* l2w = (const float*)d_in[17];
    const float* l2b = (const float*)d_in[18];
    float* out = (float*)d_out;

    const int* srcp = ei;
    const int* dstp = ei + NE;

    // workspace layout
    char* w = (char*)d_ws;
    float* dinv      = (float*)w;               w += sizeof(float) * NN;
    float* htmpA     = (float*)w;               w += sizeof(float) * NN * 32;
    float* htmpB     = (float*)w;               w += sizeof(float) * NN * 32;
    float* h1        = (float*)w;               w += sizeof(float) * NN * 32;
    float* h2        = (float*)w;               w += sizeof(float) * NN * 32;  // ebuf aliases here
    float* h3        = (float*)w;               w += sizeof(float) * NN * 32;
    float* h4        = (float*)w;               w += sizeof(float) * NN;
    int*   rowptr    = (int*)w;                 w += sizeof(int) * (NN + 1);
    int*   hist1     = (int*)w;                 w += sizeof(int) * NBUCK * NB1;
    int*   offs      = (int*)w;                 w += sizeof(int) * NBUCK * NB1;
    int*   totals    = (int*)w;                 w += sizeof(int) * NBUCK;
    int*   bucketStart = (int*)w;               w += sizeof(int) * (NBUCK + 1);
    int*   csr_src   = (int*)w;                 w += sizeof(int) * NE;
    int*   starts    = (int*)w;                 w += sizeof(int) * (NG + 1);

    // ebuf (6.55 MB) aliases h2 (13.1 MB): h2 is first written by agg layer 2,
    // long after p2 has consumed ebuf.
    unsigned int* ebuf = (unsigned int*)h2;

    // CSR build (no global atomics) + dense1 + starts
    fused_front_kernel<<<NB1 + 800 + 400, 256, 0, stream>>>(dstp, hist1, x, W1, htmpA,
                                                            batch, starts);
    s1a_kernel<<<NBUCK, 256, 0, stream>>>(hist1, offs, totals);
    s1b_kernel<<<1, 256, 0, stream>>>(totals, bucketStart, rowptr);
    p1_kernel<<<NB1, 256, 0, stream>>>(srcp, dstp, offs, bucketStart, ebuf);
    p2_kernel<<<NBUCK, 256, 0, stream>>>(ebuf, bucketStart, csr_src, rowptr, dinv);

    // layer 1 agg (+ fused dense W2): htmpA -> h1, htmpB
    gcn_aggd_kernel<32><<<NN / 32, 256, 0, stream>>>(rowptr, csr_src, htmpA, dinv, b1,
                                                     W2, h1, htmpB);
    // layer 2 agg (+ fused dense W3): htmpB -> h2, htmpA
    gcn_aggd_kernel<32><<<NN / 32, 256, 0, stream>>>(rowptr, csr_src, htmpB, dinv, b2,
                                                     W3, h2, htmpA);
    // layer 3 agg (+ fused dense W4 32->1): htmpA -> h3, htmpB[0:NN]
    gcn_aggd_kernel<1><<<NN / 32, 256, 0, stream>>>(rowptr, csr_src, htmpA, dinv, b3,
                                                    W4, h3, htmpB);
    // layer 4 agg: htmpB[0:NN] -> h4
    gcn_agg1_kernel<<<NN / 256, 256, 0, stream>>>(rowptr, csr_src, htmpB, dinv, b4, h4);

    // fused sort-pool + CNN head
    pool_cnn_kernel<<<NG, 256, 0, stream>>>(h1, h2, h3, h4, starts,
                                            c1w, c1b, c2w, c2b,
                                            l1w, l1b, l2w, l2b, out);
}